// Round 6
// baseline (457.861 us; speedup 1.0000x reference)
//
#include <hip/hip_runtime.h>

// MetapathGATConv fused kernel for MI355X (gfx950) — R9.
// History: R4=201 (2 barrier domains/CU, WRITE 75MB spills), R5=287 (NB=4 but
// bloated b[8]/acc[2][8] tiles -> starved), R6=313 (cap 85 -> heavy spills),
// R7=210, R8=275 (spills fixed, WRITE 51MB, but extra P1 barrier + P5 pass
// serialization cost more). Diagnosis: no pipe >30% busy; waves stall
// together because all 8 waves are barrier-locked per phase with only 2
// independent blocks/CU. R9: R4's exact per-wave tile shapes (acc[2][4]=32,
// b[4], a[2]) on NB=4/256-thread geometry, compact f16 scratch -> LDS
// 38.5KB -> 4 blocks/CU = 4 independent barrier domains at UNCHANGED cap 128
// (launch_bounds(256,4)) and unchanged 16 waves/CU. P1/P5 are two-pass per
// wave; only pass 1 of P1 needs the pre-epilogue barrier (pass 0 writes
// bufB which nobody reads during P1). True reg need ~75 < 128 -> no spills.
// Decisive: WRITE_SIZE ~25-35MB AND dur < 195, else decorrelation is dead.

#define NNODES 16384
#define NB 4
#define MR 32              // rows per WG = NB*8

typedef _Float16 f16x8 __attribute__((ext_vector_type(8)));
typedef _Float16 f16x4 __attribute__((ext_vector_type(4)));
typedef _Float16 f16x2 __attribute__((ext_vector_type(2)));
typedef float f32x4 __attribute__((ext_vector_type(4)));

#if __has_builtin(__builtin_amdgcn_fdot2)
#define FDOT2(a, b, c) __builtin_amdgcn_fdot2((a), (b), (c), false)
#else
#define FDOT2(a, b, c) ((c) + (float)(a)[0] * (float)(b)[0] + (float)(a)[1] * (float)(b)[1])
#endif

__device__ __forceinline__ f16x2 leaky2(f16x2 t) {
#if __has_builtin(__builtin_elementwise_max)
    return __builtin_elementwise_max(t, t * (f16x2){(_Float16)0.2f, (_Float16)0.2f});
#else
    const unsigned u = __builtin_bit_cast(unsigned, t) & 0x7FFF7FFFu;
    const f16x2 at = __builtin_bit_cast(f16x2, u);
    return t * (f16x2){(_Float16)0.6f, (_Float16)0.6f} +
           at * (f16x2){(_Float16)0.4f, (_Float16)0.4f};
#endif
}
__device__ __forceinline__ f16x2 relu2(f16x2 t) {
#if __has_builtin(__builtin_elementwise_max)
    return __builtin_elementwise_max(t, (f16x2){(_Float16)0.f, (_Float16)0.f});
#else
    const unsigned u = __builtin_bit_cast(unsigned, t) & 0x7FFF7FFFu;
    const f16x2 at = __builtin_bit_cast(f16x2, u);
    return (t + at) * (f16x2){(_Float16)0.5f, (_Float16)0.5f};
#endif
}

// swizzled chunk address: buffers are [rows][32 chunks of 8 f16],
// chunk index XORed with (row&7) so column-strided accesses spread banks.
__device__ __forceinline__ int swz(int row, int chunk) {
    return row * 256 + ((chunk ^ (row & 7)) << 3);
}

// ---------------- weight prep: transpose+cast to f16 W^T[n][k] ----------------
// wt rows 0-255: Wl0^T | 256-511: Wr0^T | 512-767: Wl1^T | 768-1023: Wr1^T.
__global__ void prep_weights(const float* __restrict__ Wl0, const float* __restrict__ Wr0,
                             const float* __restrict__ Wl1, const float* __restrict__ Wr1,
                             _Float16* __restrict__ wt) {
    __shared__ float tile[64 * 68];   // 64x64 + pad 4
    const int t  = threadIdx.x;
    const int m  = blockIdx.x >> 4;
    const int kt = (blockIdx.x >> 2) & 3;
    const int nt = blockIdx.x & 3;
    const float* src = (m == 0 ? Wl0 : m == 1 ? Wr0 : m == 2 ? Wl1 : Wr1) + kt * 64 * 256;
    #pragma unroll
    for (int i = 0; i < 4; ++i) {
        const int idx = i * 256 + t;     // float4 id 0..1023
        const int kk  = idx >> 4;
        const int nn  = (idx & 15) * 4;
        const float4 v = *(const float4*)&src[kk * 256 + nt * 64 + nn];
        tile[kk * 68 + nn + 0] = v.x;
        tile[kk * 68 + nn + 1] = v.y;
        tile[kk * 68 + nn + 2] = v.z;
        tile[kk * 68 + nn + 3] = v.w;
    }
    __syncthreads();
    const int n  = t >> 2;
    const int ks = (t & 3) * 16;
    f16x8 o0, o1;
    #pragma unroll
    for (int e = 0; e < 8; ++e) o0[e] = (_Float16)tile[(ks + e) * 68 + n];
    #pragma unroll
    for (int e = 0; e < 8; ++e) o1[e] = (_Float16)tile[(ks + 8 + e) * 68 + n];
    _Float16* dst = &wt[(size_t)(m * 256 + nt * 64 + n) * 256 + kt * 64 + ks];
    *(f16x8*)dst = o0;
    *(f16x8*)(dst + 8) = o1;
}

__launch_bounds__(256, 4)
__global__ void gat_fused(const float* __restrict__ x,
                          const float* __restrict__ bl0, const float* __restrict__ br0,
                          const float* __restrict__ att0, const float* __restrict__ bias0,
                          const float* __restrict__ bl1, const float* __restrict__ br1,
                          const float* __restrict__ att1, const float* __restrict__ bias1,
                          const _Float16* __restrict__ wt,
                          float* __restrict__ out) {
    __shared__ _Float16 bufA[MR * 256];   // 16 KB: relu(x) -> xr0 -> h1
    __shared__ _Float16 bufB[MR * 256];   // 16 KB: xl0 -> xl1
    __shared__ _Float16 aw[MR * 4 * 8];   // 2 KB: alpha0 (f16)
    __shared__ _Float16 xrsH[NB * 256];   // 2 KB: xr_self (f16)
    __shared__ float lgs[NB * 32];        // 512 B: layer-1 logits
    __shared__ float al1[NB * 32];        // 512 B: alpha1
    __shared__ _Float16 attH[768];        // 1.5 KB: att0 | att1 | bias0 (f16)

    const int tid  = threadIdx.x;
    const int bg   = blockIdx.x;
    const int lane = tid & 63;
    const int wv   = tid >> 6;          // 0..3
    const int lr   = lane & 15;
    const int lq   = lane >> 4;

    // ---------------- P0: bufA = f16(relu(x)); cache att0/att1/bias0 as f16 ----------------
    {
        const float4* src = (const float4*)(x + (size_t)bg * (MR * 256));
        #pragma unroll
        for (int it = 0; it < 4; ++it) {
            const int g   = it * 256 + tid;   // 8-elem chunk id, 0..1023
            const int row = g >> 5;
            const int c   = g & 31;
            const float4 v0 = src[2 * g];
            const float4 v1 = src[2 * g + 1];
            f16x8 s;
            s[0] = (_Float16)fmaxf(v0.x, 0.f); s[1] = (_Float16)fmaxf(v0.y, 0.f);
            s[2] = (_Float16)fmaxf(v0.z, 0.f); s[3] = (_Float16)fmaxf(v0.w, 0.f);
            s[4] = (_Float16)fmaxf(v1.x, 0.f); s[5] = (_Float16)fmaxf(v1.y, 0.f);
            s[6] = (_Float16)fmaxf(v1.z, 0.f); s[7] = (_Float16)fmaxf(v1.w, 0.f);
            *(f16x8*)&bufA[swz(row, c)] = s;
        }
        attH[tid]       = (_Float16)att0[tid];
        attH[256 + tid] = (_Float16)att1[tid];
        attH[512 + tid] = (_Float16)bias0[tid];
    }
    __syncthreads();

    // ---------------- P1: GEMM0 C[32][512] = relu(x) @ [Wl0|Wr0], two n-half passes ----------------
    // Pass np: all 4 waves cover 256 cols (wave wv owns 64). np=0 -> xl/bufB,
    // np=1 -> xr/bufA. R4's per-wave shape: acc[2][4]=32 acc regs, a[2], b[4].
    // Pass 0 writes bufB (not read during P1) -> NO barrier. Pass 1 overwrites
    // bufA -> one barrier between its K-loop and epilogue (all bufA reads done).
    {
        #pragma unroll
        for (int np = 0; np < 2; ++np) {
            f32x4 acc[2][4];
            #pragma unroll
            for (int m = 0; m < 2; ++m)
                #pragma unroll
                for (int n = 0; n < 4; ++n)
                    acc[m][n] = f32x4{0.f, 0.f, 0.f, 0.f};
            #pragma unroll
            for (int kt = 0; kt < 8; ++kt) {
                const int koff = kt * 32 + lq * 8;
                f16x8 a[2], b[4];
                #pragma unroll
                for (int m = 0; m < 2; ++m)
                    a[m] = *(const f16x8*)&bufA[swz(m * 16 + lr, kt * 4 + lq)];
                #pragma unroll
                for (int n = 0; n < 4; ++n)
                    b[n] = *(const f16x8*)&wt[(size_t)(np * 256 + wv * 64 + n * 16 + lr) * 256 + koff];
                #pragma unroll
                for (int m = 0; m < 2; ++m)
                    #pragma unroll
                    for (int n = 0; n < 4; ++n)
                        acc[m][n] = __builtin_amdgcn_mfma_f32_16x16x32_f16(a[m], b[n], acc[m][n], 0, 0, 0);
            }
            if (np == 1) __syncthreads();   // all bufA reads complete before xr overwrite
            _Float16* dstbuf = (np == 0) ? bufB : bufA;
            const float* bv  = (np == 0) ? bl0 : br0;
            #pragma unroll
            for (int n = 0; n < 4; ++n) {
                const int cl   = wv * 64 + n * 16 + lr;   // 0..255 within dst buffer
                const float bias = bv[cl];
                const int ch   = cl >> 3, ce = cl & 7;
                #pragma unroll
                for (int m = 0; m < 2; ++m)
                    #pragma unroll
                    for (int r = 0; r < 4; ++r) {
                        const int row = m * 16 + lq * 4 + r;
                        dstbuf[swz(row, ch) + ce] = (_Float16)(acc[m][n][r] + bias);
                    }
            }
        }
    }
    __syncthreads();

    // ---------------- P2: layer-0 logits + softmax over j -> alpha0 (f16) ----------------
    // thread = (n, i, h, jh): 4 j-logits (R4 mapping, NB=4). Depth-1 prefetch
    // over cc: 1 xr + 1 att + 4 xl reads issued for cc+1 before computing cc.
    {
        const int n  = tid >> 6;          // node 0..3
        const int i  = (tid >> 3) & 7;
        const int h  = (tid >> 1) & 3;
        const int jh = tid & 1;
        const int rowR = n * 8 + i;
        f16x8 xrb[2], abuf[2], lbuf[2][4];
        {
            const int c3 = (2 * h) & 7;
            xrb[0]  = *(const f16x8*)&bufA[swz(rowR, h * 8 + c3)];
            abuf[0] = *(const f16x8*)&attH[h * 64 + c3 * 8];
            #pragma unroll
            for (int jj = 0; jj < 4; ++jj)
                lbuf[0][jj] = *(const f16x8*)&bufB[swz(n * 8 + jh * 4 + jj, h * 8 + c3)];
        }
        float lg[4] = {0.f, 0.f, 0.f, 0.f};
        #pragma unroll
        for (int cc = 0; cc < 8; ++cc) {
            const int cur = cc & 1, nxt = cur ^ 1;
            if (cc < 7) {
                const int c3n = (cc + 1 + 2 * h) & 7;
                xrb[nxt]  = *(const f16x8*)&bufA[swz(rowR, h * 8 + c3n)];
                abuf[nxt] = *(const f16x8*)&attH[h * 64 + c3n * 8];
                #pragma unroll
                for (int jj = 0; jj < 4; ++jj)
                    lbuf[nxt][jj] = *(const f16x8*)&bufB[swz(n * 8 + jh * 4 + jj, h * 8 + c3n)];
            }
            const f16x8 x8 = xrb[cur];
            const f16x2 x2[4] = {{x8[0], x8[1]}, {x8[2], x8[3]}, {x8[4], x8[5]}, {x8[6], x8[7]}};
            const f16x8 a8 = abuf[cur];
            const f16x2 a2[4] = {{a8[0], a8[1]}, {a8[2], a8[3]}, {a8[4], a8[5]}, {a8[6], a8[7]}};
            #pragma unroll
            for (int jj = 0; jj < 4; ++jj) {
                const f16x8 l8 = lbuf[cur][jj];
                const f16x2 l2[4] = {{l8[0], l8[1]}, {l8[2], l8[3]}, {l8[4], l8[5]}, {l8[6], l8[7]}};
                #pragma unroll
                for (int p = 0; p < 4; ++p) {
                    const f16x2 t = leaky2(x2[p] + l2[p]);
                    lg[jj] = FDOT2(t, a2[p], lg[jj]);
                }
            }
        }
        float mx = fmaxf(fmaxf(lg[0], lg[1]), fmaxf(lg[2], lg[3]));
        mx = fmaxf(mx, __shfl_xor(mx, 1));
        float ex[4], ssum = 0.f;
        #pragma unroll
        for (int jj = 0; jj < 4; ++jj) { ex[jj] = __expf(lg[jj] - mx); ssum += ex[jj]; }
        const float tot = ssum + __shfl_xor(ssum, 1);
        const float inv = 1.f / tot;
        f16x4 w;
        #pragma unroll
        for (int jj = 0; jj < 4; ++jj) w[jj] = (_Float16)(ex[jj] * inv);
        *(f16x4*)&aw[(rowR * 4 + h) * 8 + jh * 4] = w;
    }
    __syncthreads();

    // ---------------- P3: h1 = relu(alpha0 @ xl0 + bias0) -> bufA (packed f16) ----------------
    // thread = (row, h, half): 32 output cols; j-loop double-buffered.
    {
        const int row  = tid >> 3;        // 0..31
        const int sub  = tid & 7;
        const int h    = sub >> 1;
        const int half = sub & 1;
        const int nn   = row >> 3;        // node 0..3
        const int cb   = h * 8 + half * 4;
        const f16x8 ah8 = *(const f16x8*)&aw[(row * 4 + h) * 8];
        f16x2 acc2[16];
        #pragma unroll
        for (int p = 0; p < 16; ++p) acc2[p] = (f16x2){(_Float16)0.f, (_Float16)0.f};
        f16x8 vbuf[2][4];
        #pragma unroll
        for (int cc = 0; cc < 4; ++cc)
            vbuf[0][cc] = *(const f16x8*)&bufB[swz(nn * 8, cb + ((cc + h) & 3))];
        #pragma unroll
        for (int j = 0; j < 8; ++j) {
            const int cur = j & 1, nxt = cur ^ 1;
            if (j < 7) {
                #pragma unroll
                for (int cc = 0; cc < 4; ++cc)
                    vbuf[nxt][cc] = *(const f16x8*)&bufB[swz(nn * 8 + j + 1, cb + ((cc + h) & 3))];
            }
            const f16x2 a2 = {ah8[j], ah8[j]};
            #pragma unroll
            for (int cc = 0; cc < 4; ++cc) {
                const f16x8 v = vbuf[cur][cc];
                acc2[cc * 4 + 0] += f16x2{v[0], v[1]} * a2;
                acc2[cc * 4 + 1] += f16x2{v[2], v[3]} * a2;
                acc2[cc * 4 + 2] += f16x2{v[4], v[5]} * a2;
                acc2[cc * 4 + 3] += f16x2{v[6], v[7]} * a2;
            }
        }
        #pragma unroll
        for (int cc = 0; cc < 4; ++cc) {
            const int c = cb + ((cc + h) & 3);
            const f16x8 b8 = *(const f16x8*)&attH[512 + c * 8];
            f16x8 s;
            #pragma unroll
            for (int p = 0; p < 4; ++p) {
                const f16x2 r = relu2(acc2[cc * 4 + p] + f16x2{b8[2 * p], b8[2 * p + 1]});
                s[2 * p]     = r[0];
                s[2 * p + 1] = r[1];
            }
            *(f16x8*)&bufA[swz(row, c)] = s;
        }
    }
    __syncthreads();

    // ---------------- P5: GEMM1 two passes: xl1 = h1@Wl1+bl1 -> bufB ; xrs -> xrsH ----------------
    // bufA read-only; bufB/xrsH write-only -> no internal barriers.
    // Pass 0: xl1, acc[2][4]=32 regs. Pass 1: xrs only, accr[4]=16 regs.
    {
        const _Float16* W1l = wt + 512 * 256;
        const _Float16* W1r = wt + 768 * 256;
        // ---- pass 0: xl1 (wave wv owns cols wv*64..wv*64+63) ----
        {
            f32x4 accl[2][4];
            #pragma unroll
            for (int m = 0; m < 2; ++m)
                #pragma unroll
                for (int n = 0; n < 4; ++n)
                    accl[m][n] = f32x4{0.f, 0.f, 0.f, 0.f};
            #pragma unroll
            for (int kt = 0; kt < 8; ++kt) {
                const int koff = kt * 32 + lq * 8;
                f16x8 a[2], bl[4];
                #pragma unroll
                for (int m = 0; m < 2; ++m)
                    a[m] = *(const f16x8*)&bufA[swz(m * 16 + lr, kt * 4 + lq)];
                #pragma unroll
                for (int n = 0; n < 4; ++n)
                    bl[n] = *(const f16x8*)&W1l[(size_t)(wv * 64 + n * 16 + lr) * 256 + koff];
                #pragma unroll
                for (int m = 0; m < 2; ++m)
                    #pragma unroll
                    for (int n = 0; n < 4; ++n)
                        accl[m][n] = __builtin_amdgcn_mfma_f32_16x16x32_f16(a[m], bl[n], accl[m][n], 0, 0, 0);
            }
            #pragma unroll
            for (int n = 0; n < 4; ++n) {
                const int col = wv * 64 + n * 16 + lr;   // 0..255
                const float b1 = bl1[col];
                const int ch = col >> 3, ce = col & 7;
                #pragma unroll
                for (int m = 0; m < 2; ++m)
                    #pragma unroll
                    for (int r = 0; r < 4; ++r) {
                        const int row = m * 16 + lq * 4 + r;
                        bufB[swz(row, ch) + ce] = (_Float16)(accl[m][n][r] + b1);
                    }
            }
        }
        // ---- pass 1: xrs = self @ Wr1 + br1 (f16 into xrsH) ----
        {
            f32x4 accr[4];
            #pragma unroll
            for (int n = 0; n < 4; ++n) accr[n] = f32x4{0.f, 0.f, 0.f, 0.f};
            const int rowS = (lr & 3) * 8 + 7;    // self row of node (lr&3)
            #pragma unroll
            for (int kt = 0; kt < 8; ++kt) {
                const int koff = kt * 32 + lq * 8;
                const f16x8 as = *(const f16x8*)&bufA[swz(rowS, kt * 4 + lq)];
                f16x8 br[4];
                #pragma unroll
                for (int n = 0; n < 4; ++n)
                    br[n] = *(const f16x8*)&W1r[(size_t)(wv * 64 + n * 16 + lr) * 256 + koff];
                #pragma unroll
                for (int n = 0; n < 4; ++n)
                    accr[n] = __builtin_amdgcn_mfma_f32_16x16x32_f16(as, br[n], accr[n], 0, 0, 0);
            }
            #pragma unroll
            for (int n = 0; n < 4; ++n) {
                const int col = wv * 64 + n * 16 + lr;   // 0..255
                const float b2 = br1[col];
                if (lq == 0) {
                    #pragma unroll
                    for (int r = 0; r < 4; ++r)          // D rows 0..3 = nodes 0..3
                        xrsH[r * 256 + col] = (_Float16)(accr[n][r] + b2);
                }
            }
        }
    }
    __syncthreads();

    // ---------------- P6: layer-1 logits, softmax over r -> betas + alpha1 ----------------
    // 128 active threads; depth-1 prefetch (1 xrs + 1 xl1 + 1 att per step).
    {
        const int n  = tid >> 5;          // valid for tid<128: 0..3
        const int rr = (tid >> 2) & 7;
        const int h  = tid & 3;
        float lg = 0.f;
        if (tid < 128) {
            const int rowj = n * 8 + rr;
            f16x8 xbuf[2], lbuf[2], abuf[2];
            {
                const int c = h * 8 + ((2 * h) & 7);
                xbuf[0] = *(const f16x8*)&xrsH[n * 256 + c * 8];
                lbuf[0] = *(const f16x8*)&bufB[swz(rowj, c)];
                abuf[0] = *(const f16x8*)&attH[256 + c * 8];
            }
            #pragma unroll
            for (int cc = 0; cc < 8; ++cc) {
                const int cur = cc & 1, nxt = cur ^ 1;
                if (cc < 7) {
                    const int cn = h * 8 + ((cc + 1 + 2 * h) & 7);
                    xbuf[nxt] = *(const f16x8*)&xrsH[n * 256 + cn * 8];
                    lbuf[nxt] = *(const f16x8*)&bufB[swz(rowj, cn)];
                    abuf[nxt] = *(const f16x8*)&attH[256 + cn * 8];
                }
                const f16x8 x8 = xbuf[cur];
                const f16x8 l8 = lbuf[cur];
                const f16x8 a8 = abuf[cur];
                #pragma unroll
                for (int p = 0; p < 4; ++p) {
                    const f16x2 xp = {x8[2 * p], x8[2 * p + 1]};
                    const f16x2 lp = {l8[2 * p], l8[2 * p + 1]};
                    const f16x2 ap = {a8[2 * p], a8[2 * p + 1]};
                    const f16x2 t = leaky2(xp + lp);
                    lg = FDOT2(t, ap, lg);
                }
            }
            lgs[tid] = lg;
        }
        __syncthreads();
        if (tid < 128) {
            float M = -1e30f;
            float l[8];
            #pragma unroll
            for (int j = 0; j < 8; ++j) {
                l[j] = lgs[n * 32 + j * 4 + h];
                M = fmaxf(M, l[j]);
            }
            float S = 0.f;
            #pragma unroll
            for (int j = 0; j < 8; ++j) S += __expf(l[j] - M);
            const float a = __expf(lg - M) / S;
            al1[tid] = a;
            out[(size_t)NNODES * 256 + (size_t)(bg * NB + n) * 32 + rr * 4 + h] = a;  // betas
        }
    }
    __syncthreads();

    // ---------------- P7: out = relu(alpha1 @ xl1 + bias1) — all reads hoisted ----------------
    {
        const int n  = tid >> 6;          // node 0..3
        const int q  = tid & 63;
        const int c0 = q * 4;
        const int h  = q >> 4;
        f16x4 v[8];
        float a[8];
        #pragma unroll
        for (int r = 0; r < 8; ++r) {
            v[r] = *(const f16x4*)&bufB[swz(n * 8 + r, q >> 1) + (q & 1) * 4];
            a[r] = al1[n * 32 + r * 4 + h];
        }
        float o0 = 0.f, o1 = 0.f, o2 = 0.f, o3 = 0.f;
        #pragma unroll
        for (int r = 0; r < 8; ++r) {
            o0 = fmaf((float)v[r][0], a[r], o0);
            o1 = fmaf((float)v[r][1], a[r], o1);
            o2 = fmaf((float)v[r][2], a[r], o2);
            o3 = fmaf((float)v[r][3], a[r], o3);
        }
        float4 res;
        res.x = fmaxf(o0 + bias1[c0 + 0], 0.f);
        res.y = fmaxf(o1 + bias1[c0 + 1], 0.f);
        res.z = fmaxf(o2 + bias1[c0 + 2], 0.f);
        res.w = fmaxf(o3 + bias1[c0 + 3], 0.f);
        *(float4*)&out[(size_t)(bg * NB + n) * 256 + c0] = res;
    }
}

extern "C" void kernel_launch(void* const* d_in, const int* in_sizes, int n_in,
                              void* d_out, int out_size, void* d_ws, size_t ws_size,
                              hipStream_t stream) {
    const float* x     = (const float*)d_in[0];
    const float* Wl0   = (const float*)d_in[1];
    const float* bl0   = (const float*)d_in[2];
    const float* Wr0   = (const float*)d_in[3];
    const float* br0   = (const float*)d_in[4];
    const float* att0  = (const float*)d_in[5];
    const float* bias0 = (const float*)d_in[6];
    const float* Wl1   = (const float*)d_in[7];
    const float* bl1   = (const float*)d_in[8];
    const float* Wr1   = (const float*)d_in[9];
    const float* br1   = (const float*)d_in[10];
    const float* att1  = (const float*)d_in[11];
    const float* bias1 = (const float*)d_in[12];
    _Float16* wt = (_Float16*)d_ws;   // 512 KB
    float* out = (float*)d_out;

    prep_weights<<<64, 256, 0, stream>>>(Wl0, Wr0, Wl1, Wr1, wt);
    gat_fused<<<NNODES / NB, 256, 0, stream>>>(x, bl0, br0, att0, bias0,
                                               bl1, br1, att1, bias1, wt, out);
}

// Round 7
// 443.196 us; speedup vs baseline: 1.0331x; 1.0331x over previous
//
#include <hip/hip_runtime.h>

// MetapathGATConv for MI355X (gfx950) — R10: two-kernel split.
// 6 rounds of fused-kernel restructuring all lost to R4's 201us; the phase
// time decomposition was never measured. R10 splits at the GEMM0/attention
// boundary: K1 gemm0 streams X1=[xl0|xr0] (f16, 128MiB workspace) as a clean
// tiled GEMM; K2 gat_attn = R4's proven P2..P7 verbatim with X1 staging.
// Fallback: if ws_size < 135MB, run the verbatim R4 fused kernel (201us).
// The two dispatch durations in rocprof finally decompose the time.

#define NNODES 16384
#define NB 8
#define MR 64              // rows per WG in attention kernel = NB*8

typedef _Float16 f16x8 __attribute__((ext_vector_type(8)));
typedef _Float16 f16x4 __attribute__((ext_vector_type(4)));
typedef _Float16 f16x2 __attribute__((ext_vector_type(2)));
typedef float f32x4 __attribute__((ext_vector_type(4)));

#if __has_builtin(__builtin_amdgcn_fdot2)
#define FDOT2(a, b, c) __builtin_amdgcn_fdot2((a), (b), (c), false)
#else
#define FDOT2(a, b, c) ((c) + (float)(a)[0] * (float)(b)[0] + (float)(a)[1] * (float)(b)[1])
#endif

__device__ __forceinline__ f16x2 pk2(float a, float b) {
    return __builtin_bit_cast(f16x2, __builtin_amdgcn_cvt_pkrtz(a, b));
}

__device__ __forceinline__ f16x2 leaky2(f16x2 t) {
#if __has_builtin(__builtin_elementwise_max)
    return __builtin_elementwise_max(t, t * (f16x2){(_Float16)0.2f, (_Float16)0.2f});
#else
    const unsigned u = __builtin_bit_cast(unsigned, t) & 0x7FFF7FFFu;
    const f16x2 at = __builtin_bit_cast(f16x2, u);
    return t * (f16x2){(_Float16)0.6f, (_Float16)0.6f} +
           at * (f16x2){(_Float16)0.4f, (_Float16)0.4f};
#endif
}
__device__ __forceinline__ f16x2 relu2(f16x2 t) {
#if __has_builtin(__builtin_elementwise_max)
    return __builtin_elementwise_max(t, (f16x2){(_Float16)0.f, (_Float16)0.f});
#else
    const unsigned u = __builtin_bit_cast(unsigned, t) & 0x7FFF7FFFu;
    const f16x2 at = __builtin_bit_cast(f16x2, u);
    return (t + at) * (f16x2){(_Float16)0.5f, (_Float16)0.5f};
#endif
}

// swizzled chunk address: buffers are [rows][32 chunks of 8 f16],
// chunk index XORed with (row&7) so column-strided accesses spread banks.
__device__ __forceinline__ int swz(int row, int chunk) {
    return row * 256 + ((chunk ^ (row & 7)) << 3);
}
// C-tile swizzle for gemm0 epilogue bounce: [rows][16 chunks of 8 f16].
__device__ __forceinline__ int cswz(int row, int col) {
    return row * 128 + (((col >> 3) ^ (row & 7)) << 3) + (col & 7);
}

// ---------------- weight prep: transpose+cast to f16 W^T[n][k] ----------------
// wt rows 0-255: Wl0^T | 256-511: Wr0^T | 512-767: Wl1^T | 768-1023: Wr1^T.
__global__ void prep_weights(const float* __restrict__ Wl0, const float* __restrict__ Wr0,
                             const float* __restrict__ Wl1, const float* __restrict__ Wr1,
                             _Float16* __restrict__ wt) {
    __shared__ float tile[64 * 68];   // 64x64 + pad 4
    const int t  = threadIdx.x;
    const int m  = blockIdx.x >> 4;
    const int kt = (blockIdx.x >> 2) & 3;
    const int nt = blockIdx.x & 3;
    const float* src = (m == 0 ? Wl0 : m == 1 ? Wr0 : m == 2 ? Wl1 : Wr1) + kt * 64 * 256;
    #pragma unroll
    for (int i = 0; i < 4; ++i) {
        const int idx = i * 256 + t;     // float4 id 0..1023
        const int kk  = idx >> 4;
        const int nn  = (idx & 15) * 4;
        const float4 v = *(const float4*)&src[kk * 256 + nt * 64 + nn];
        tile[kk * 68 + nn + 0] = v.x;
        tile[kk * 68 + nn + 1] = v.y;
        tile[kk * 68 + nn + 2] = v.z;
        tile[kk * 68 + nn + 3] = v.w;
    }
    __syncthreads();
    const int n  = t >> 2;
    const int ks = (t & 3) * 16;
    f16x8 o0, o1;
    #pragma unroll
    for (int e = 0; e < 8; ++e) o0[e] = (_Float16)tile[(ks + e) * 68 + n];
    #pragma unroll
    for (int e = 0; e < 8; ++e) o1[e] = (_Float16)tile[(ks + 8 + e) * 68 + n];
    _Float16* dst = &wt[(size_t)(m * 256 + nt * 64 + n) * 256 + kt * 64 + ks];
    *(f16x8*)dst = o0;
    *(f16x8*)(dst + 8) = o1;
}

// ---------------- K1: X1[131072][512] = relu(x) @ [Wl0|Wr0] + [bl0|br0] ----------------
// Block = 128 rows x 128 cols. grid = 1024 m-blocks x 4 n-blocks.
__launch_bounds__(512, 4)
__global__ void gemm0(const float* __restrict__ x,
                      const float* __restrict__ bl0, const float* __restrict__ br0,
                      const _Float16* __restrict__ wt,
                      _Float16* __restrict__ X1) {
    __shared__ _Float16 A[128 * 256];   // 64 KB: relu(x) f16 tile; reused as C bounce
    const int bid = blockIdx.x;
    const int mb = bid >> 2, nb = bid & 3;
    const int row0 = mb * 128;
    const int tid = threadIdx.x;
    const int lane = tid & 63;
    const int wv = tid >> 6;            // 0..7
    const int lr = lane & 15;
    const int lq = lane >> 4;
    const int wr = wv >> 1;             // 0..3: rows wr*32..+31
    const int wc = wv & 1;              // 0..1: cols wc*64..+63

    // stage A = f16(relu(x[row0 .. row0+127][:]))
    {
        const float4* src = (const float4*)(x + (size_t)row0 * 256);
        #pragma unroll
        for (int it = 0; it < 8; ++it) {
            const int g = it * 512 + tid;    // chunk id 0..4095
            const int row = g >> 5, c = g & 31;
            const float4 v0 = src[2 * g];
            const float4 v1 = src[2 * g + 1];
            f16x8 s;
            s[0] = (_Float16)fmaxf(v0.x, 0.f); s[1] = (_Float16)fmaxf(v0.y, 0.f);
            s[2] = (_Float16)fmaxf(v0.z, 0.f); s[3] = (_Float16)fmaxf(v0.w, 0.f);
            s[4] = (_Float16)fmaxf(v1.x, 0.f); s[5] = (_Float16)fmaxf(v1.y, 0.f);
            s[6] = (_Float16)fmaxf(v1.z, 0.f); s[7] = (_Float16)fmaxf(v1.w, 0.f);
            *(f16x8*)&A[swz(row, c)] = s;
        }
    }
    __syncthreads();

    // K loop: per-wave 32x64 output tile, acc[2][4] = 32 acc regs.
    f32x4 acc[2][4];
    #pragma unroll
    for (int m = 0; m < 2; ++m)
        #pragma unroll
        for (int n = 0; n < 4; ++n)
            acc[m][n] = f32x4{0.f, 0.f, 0.f, 0.f};
    #pragma unroll
    for (int kt = 0; kt < 8; ++kt) {
        const int koff = kt * 32 + lq * 8;
        f16x8 a[2], b[4];
        #pragma unroll
        for (int m = 0; m < 2; ++m)
            a[m] = *(const f16x8*)&A[swz(wr * 32 + m * 16 + lr, kt * 4 + lq)];
        #pragma unroll
        for (int n = 0; n < 4; ++n)
            b[n] = *(const f16x8*)&wt[(size_t)(nb * 128 + wc * 64 + n * 16 + lr) * 256 + koff];
        #pragma unroll
        for (int m = 0; m < 2; ++m)
            #pragma unroll
            for (int n = 0; n < 4; ++n)
                acc[m][n] = __builtin_amdgcn_mfma_f32_16x16x32_f16(a[m], b[n], acc[m][n], 0, 0, 0);
    }
    __syncthreads();   // all A reads done; reuse LDS as C bounce

    // bias + pack to f16 C tile in LDS (coalesced global write after)
    _Float16* Cl = A;
    #pragma unroll
    for (int n = 0; n < 4; ++n) {
        const int col  = wc * 64 + n * 16 + lr;       // 0..127 within block
        const int gcol = nb * 128 + col;              // 0..511 global
        const float bias = (gcol < 256) ? bl0[gcol] : br0[gcol - 256];
        #pragma unroll
        for (int m = 0; m < 2; ++m)
            #pragma unroll
            for (int r = 0; r < 4; ++r) {
                const int row = wr * 32 + m * 16 + lq * 4 + r;
                Cl[cswz(row, col)] = (_Float16)(acc[m][n][r] + bias);
            }
    }
    __syncthreads();

    // copy C tile to X1 (16B per thread per it, coalesced)
    #pragma unroll
    for (int it = 0; it < 4; ++it) {
        const int g = it * 512 + tid;    // 0..2047: row = g>>4, ch = g&15
        const int row = g >> 4, ch = g & 15;
        const f16x8 v = *(const f16x8*)&Cl[row * 128 + ((ch ^ (row & 7)) << 3)];
        *(f16x8*)&X1[(size_t)(row0 + row) * 512 + nb * 128 + ch * 8] = v;
    }
}

// ---------------- K2: attention chain (R4's P2..P7 verbatim; stage from X1) ----------------
__launch_bounds__(512, 4)
__global__ void gat_attn(const float* __restrict__ att0, const float* __restrict__ bias0,
                         const float* __restrict__ bl1, const float* __restrict__ br1,
                         const float* __restrict__ att1, const float* __restrict__ bias1,
                         const _Float16* __restrict__ wt,
                         const _Float16* __restrict__ X1,
                         float* __restrict__ out) {
    __shared__ _Float16 bufA[MR * 256];  // 32 KB: xr0 -> h1
    __shared__ _Float16 bufB[MR * 256];  // 32 KB: xl0 -> xl1
    __shared__ float attbuf[2304];       // 9 KB
    __shared__ _Float16 attH[768];       // 1.5 KB

    const int tid  = threadIdx.x;
    const int bg   = blockIdx.x;
    const int lane = tid & 63;
    const int wv   = tid >> 6;
    const int lr   = lane & 15;
    const int lq   = lane >> 4;

    // stage: bufB = xl0 rows, bufA = xr0 rows (from X1), attH consts
    {
        const _Float16* src = X1 + (size_t)bg * 64 * 512;
        #pragma unroll
        for (int it = 0; it < 4; ++it) {
            const int g = it * 512 + tid;   // 0..2047: row = g>>5, c = g&31
            const int row = g >> 5, c = g & 31;
            const f16x8 vl = *(const f16x8*)&src[(size_t)row * 512 + c * 8];
            const f16x8 vr = *(const f16x8*)&src[(size_t)row * 512 + 256 + c * 8];
            *(f16x8*)&bufB[swz(row, c)] = vl;
            *(f16x8*)&bufA[swz(row, c)] = vr;
        }
        if (tid < 256) {
            attH[tid]       = (_Float16)att0[tid];
            attH[512 + tid] = (_Float16)bias0[tid];
        } else {
            attH[tid]       = (_Float16)att1[tid - 256];
        }
    }
    __syncthreads();

    // ---------------- P2: layer-0 logits + softmax over j -> alpha0 ----------------
    {
        const int n  = tid >> 6;
        const int i  = (tid >> 3) & 7;
        const int h  = (tid >> 1) & 3;
        const int jh = tid & 1;
        const int rowR = n * 8 + i;
        f16x2 xr2[32];
        #pragma unroll
        for (int cc = 0; cc < 8; ++cc) {
            const int c3 = (cc + 2 * h) & 7;
            const f16x8 v = *(const f16x8*)&bufA[swz(rowR, h * 8 + c3)];
            xr2[cc * 4 + 0] = f16x2{v[0], v[1]};
            xr2[cc * 4 + 1] = f16x2{v[2], v[3]};
            xr2[cc * 4 + 2] = f16x2{v[4], v[5]};
            xr2[cc * 4 + 3] = f16x2{v[6], v[7]};
        }
        f16x8 lbuf[2][4];
        f16x8 abuf[2];
        {
            const int c3 = (2 * h) & 7;
            abuf[0] = *(const f16x8*)&attH[h * 64 + c3 * 8];
            #pragma unroll
            for (int jj = 0; jj < 4; ++jj)
                lbuf[0][jj] = *(const f16x8*)&bufB[swz(n * 8 + jh * 4 + jj, h * 8 + c3)];
        }
        float lg[4] = {0.f, 0.f, 0.f, 0.f};
        #pragma unroll
        for (int cc = 0; cc < 8; ++cc) {
            const int cur = cc & 1, nxt = cur ^ 1;
            if (cc < 7) {
                const int c3n = (cc + 1 + 2 * h) & 7;
                abuf[nxt] = *(const f16x8*)&attH[h * 64 + c3n * 8];
                #pragma unroll
                for (int jj = 0; jj < 4; ++jj)
                    lbuf[nxt][jj] = *(const f16x8*)&bufB[swz(n * 8 + jh * 4 + jj, h * 8 + c3n)];
            }
            const f16x8 a8 = abuf[cur];
            const f16x2 a2[4] = {{a8[0], a8[1]}, {a8[2], a8[3]}, {a8[4], a8[5]}, {a8[6], a8[7]}};
            #pragma unroll
            for (int jj = 0; jj < 4; ++jj) {
                const f16x8 l8 = lbuf[cur][jj];
                const f16x2 l2[4] = {{l8[0], l8[1]}, {l8[2], l8[3]}, {l8[4], l8[5]}, {l8[6], l8[7]}};
                #pragma unroll
                for (int p = 0; p < 4; ++p) {
                    const f16x2 t = leaky2(xr2[cc * 4 + p] + l2[p]);
                    lg[jj] = FDOT2(t, a2[p], lg[jj]);
                }
            }
        }
        float mx = fmaxf(fmaxf(lg[0], lg[1]), fmaxf(lg[2], lg[3]));
        mx = fmaxf(mx, __shfl_xor(mx, 1));
        float ex[4], ssum = 0.f;
        #pragma unroll
        for (int jj = 0; jj < 4; ++jj) { ex[jj] = __expf(lg[jj] - mx); ssum += ex[jj]; }
        const float tot = ssum + __shfl_xor(ssum, 1);
        const float inv = 1.f / tot;
        #pragma unroll
        for (int jj = 0; jj < 4; ++jj)
            attbuf[((n * 8 + i) * 4 + h) * 8 + jh * 4 + jj] = ex[jj] * inv;
    }
    __syncthreads();

    // ---------------- P3: h1 = relu(alpha0 @ xl0 + bias0) -> bufA ----------------
    {
        const int row  = tid >> 3;
        const int sub  = tid & 7;
        const int h    = sub >> 1;
        const int half = sub & 1;
        const int nn   = row >> 3;
        const int cb   = h * 8 + half * 4;
        _Float16 ahv[8];
        #pragma unroll
        for (int j = 0; j < 8; ++j) ahv[j] = (_Float16)attbuf[(row * 4 + h) * 8 + j];
        f16x2 acc2[16];
        #pragma unroll
        for (int p = 0; p < 16; ++p) acc2[p] = (f16x2){(_Float16)0.f, (_Float16)0.f};
        f16x8 vbuf[2][4];
        #pragma unroll
        for (int cc = 0; cc < 4; ++cc)
            vbuf[0][cc] = *(const f16x8*)&bufB[swz(nn * 8, cb + ((cc + h) & 3))];
        #pragma unroll
        for (int j = 0; j < 8; ++j) {
            const int cur = j & 1, nxt = cur ^ 1;
            if (j < 7) {
                #pragma unroll
                for (int cc = 0; cc < 4; ++cc)
                    vbuf[nxt][cc] = *(const f16x8*)&bufB[swz(nn * 8 + j + 1, cb + ((cc + h) & 3))];
            }
            const f16x2 a2 = {ahv[j], ahv[j]};
            #pragma unroll
            for (int cc = 0; cc < 4; ++cc) {
                const f16x8 v = vbuf[cur][cc];
                acc2[cc * 4 + 0] += f16x2{v[0], v[1]} * a2;
                acc2[cc * 4 + 1] += f16x2{v[2], v[3]} * a2;
                acc2[cc * 4 + 2] += f16x2{v[4], v[5]} * a2;
                acc2[cc * 4 + 3] += f16x2{v[6], v[7]} * a2;
            }
        }
        #pragma unroll
        for (int cc = 0; cc < 4; ++cc) {
            const int c = cb + ((cc + h) & 3);
            const f16x8 b8 = *(const f16x8*)&attH[512 + c * 8];
            f16x8 s;
            #pragma unroll
            for (int p = 0; p < 4; ++p) {
                const f16x2 r = relu2(acc2[cc * 4 + p] + f16x2{b8[2 * p], b8[2 * p + 1]});
                s[2 * p]     = r[0];
                s[2 * p + 1] = r[1];
            }
            *(f16x8*)&bufA[swz(row, c)] = s;
        }
    }
    __syncthreads();

    // ---------------- P5: GEMM1: xl1 -> bufB ; xrs -> attbuf ----------------
    {
        f32x4 accl[4][2], accr[2];
        #pragma unroll
        for (int m = 0; m < 4; ++m)
            #pragma unroll
            for (int n = 0; n < 2; ++n)
                accl[m][n] = f32x4{0.f, 0.f, 0.f, 0.f};
        #pragma unroll
        for (int n = 0; n < 2; ++n) accr[n] = f32x4{0.f, 0.f, 0.f, 0.f};
        const _Float16* W1l = wt + 512 * 256;
        const _Float16* W1r = wt + 768 * 256;
        const int rowS = (lr & 7) * 8 + 7;
        #pragma unroll
        for (int kt = 0; kt < 8; ++kt) {
            const int koff = kt * 32 + lq * 8;
            f16x8 a[4], as, bl[2], br[2];
            #pragma unroll
            for (int m = 0; m < 4; ++m)
                a[m] = *(const f16x8*)&bufA[swz(m * 16 + lr, kt * 4 + lq)];
            as = *(const f16x8*)&bufA[swz(rowS, kt * 4 + lq)];
            #pragma unroll
            for (int n = 0; n < 2; ++n) {
                bl[n] = *(const f16x8*)&W1l[(size_t)(wv * 32 + n * 16 + lr) * 256 + koff];
                br[n] = *(const f16x8*)&W1r[(size_t)(wv * 32 + n * 16 + lr) * 256 + koff];
            }
            #pragma unroll
            for (int m = 0; m < 4; ++m)
                #pragma unroll
                for (int n = 0; n < 2; ++n)
                    accl[m][n] = __builtin_amdgcn_mfma_f32_16x16x32_f16(a[m], bl[n], accl[m][n], 0, 0, 0);
            #pragma unroll
            for (int n = 0; n < 2; ++n)
                accr[n] = __builtin_amdgcn_mfma_f32_16x16x32_f16(as, br[n], accr[n], 0, 0, 0);
        }
        #pragma unroll
        for (int n = 0; n < 2; ++n) {
            const int col = wv * 32 + n * 16 + lr;
            const float b1 = bl1[col], b2 = br1[col];
            const int ch = col >> 3, ce = col & 7;
            #pragma unroll
            for (int m = 0; m < 4; ++m)
                #pragma unroll
                for (int r = 0; r < 4; ++r) {
                    const int row = m * 16 + lq * 4 + r;
                    bufB[swz(row, ch) + ce] = (_Float16)(accl[m][n][r] + b1);
                }
            if (lq < 2) {
                #pragma unroll
                for (int r = 0; r < 4; ++r) {
                    const int node = lq * 4 + r;
                    attbuf[node * 256 + col] = accr[n][r] + b2;
                }
            }
        }
    }
    __syncthreads();

    // ---------------- P6: layer-1 logits, softmax over r -> betas + alpha1 ----------------
    {
        const int n  = tid >> 5;
        const int rr = (tid >> 2) & 7;
        const int h  = tid & 3;
        float lg = 0.f;
        if (tid < 256) {
            const int rowj = n * 8 + rr;
            float4 xbuf0[2], xbuf1[2];
            f16x8 lbuf[2], abuf[2];
            {
                const int c = h * 8 + ((2 * h) & 7);
                xbuf0[0] = *(const float4*)&attbuf[n * 256 + c * 8];
                xbuf1[0] = *(const float4*)&attbuf[n * 256 + c * 8 + 4];
                lbuf[0]  = *(const f16x8*)&bufB[swz(rowj, c)];
                abuf[0]  = *(const f16x8*)&attH[256 + c * 8];
            }
            #pragma unroll
            for (int cc = 0; cc < 8; ++cc) {
                const int cur = cc & 1, nxt = cur ^ 1;
                if (cc < 7) {
                    const int cn = h * 8 + ((cc + 1 + 2 * h) & 7);
                    xbuf0[nxt] = *(const float4*)&attbuf[n * 256 + cn * 8];
                    xbuf1[nxt] = *(const float4*)&attbuf[n * 256 + cn * 8 + 4];
                    lbuf[nxt]  = *(const f16x8*)&bufB[swz(rowj, cn)];
                    abuf[nxt]  = *(const f16x8*)&attH[256 + cn * 8];
                }
                const float4 r0 = xbuf0[cur], r1 = xbuf1[cur];
                const f16x2 x2[4] = {pk2(r0.x, r0.y), pk2(r0.z, r0.w),
                                     pk2(r1.x, r1.y), pk2(r1.z, r1.w)};
                const f16x8 l8 = lbuf[cur];
                const f16x2 l2[4] = {{l8[0], l8[1]}, {l8[2], l8[3]}, {l8[4], l8[5]}, {l8[6], l8[7]}};
                const f16x8 a8 = abuf[cur];
                const f16x2 a2[4] = {{a8[0], a8[1]}, {a8[2], a8[3]}, {a8[4], a8[5]}, {a8[6], a8[7]}};
                #pragma unroll
                for (int p = 0; p < 4; ++p) {
                    const f16x2 t = leaky2(x2[p] + l2[p]);
                    lg = FDOT2(t, a2[p], lg);
                }
            }
        }
        __syncthreads();
        if (tid < 256) attbuf[2048 + tid] = lg;
        __syncthreads();
        if (tid < 256) {
            float M = -1e30f;
            float l[8];
            #pragma unroll
            for (int j = 0; j < 8; ++j) {
                l[j] = attbuf[2048 + n * 32 + j * 4 + h];
                M = fmaxf(M, l[j]);
            }
            float S = 0.f;
            #pragma unroll
            for (int j = 0; j < 8; ++j) S += __expf(l[j] - M);
            const float a = __expf(lg - M) / S;
            attbuf[tid] = a;
            out[(size_t)NNODES * 256 + (size_t)(bg * NB + n) * 32 + rr * 4 + h] = a;
        }
    }
    __syncthreads();

    // ---------------- P7: out = relu(alpha1 @ xl1 + bias1) ----------------
    {
        const int n  = tid >> 6;
        const int q  = tid & 63;
        const int c0 = q * 4;
        const int h  = q >> 4;
        f16x4 v[8];
        float a[8];
        #pragma unroll
        for (int r = 0; r < 8; ++r) {
            v[r] = *(const f16x4*)&bufB[swz(n * 8 + r, q >> 1) + (q & 1) * 4];
            a[r] = attbuf[n * 32 + r * 4 + h];
        }
        float o0 = 0.f, o1 = 0.f, o2 = 0.f, o3 = 0.f;
        #pragma unroll
        for (int r = 0; r < 8; ++r) {
            o0 = fmaf((float)v[r][0], a[r], o0);
            o1 = fmaf((float)v[r][1], a[r], o1);
            o2 = fmaf((float)v[r][2], a[r], o2);
            o3 = fmaf((float)v[r][3], a[r], o3);
        }
        float4 res;
        res.x = fmaxf(o0 + bias1[c0 + 0], 0.f);
        res.y = fmaxf(o1 + bias1[c0 + 1], 0.f);
        res.z = fmaxf(o2 + bias1[c0 + 2], 0.f);
        res.w = fmaxf(o3 + bias1[c0 + 3], 0.f);
        *(float4*)&out[(size_t)(bg * NB + n) * 256 + c0] = res;
    }
}

// ---------------- Fallback: R4 fused kernel, verbatim (201us proven) ----------------
__launch_bounds__(512, 4)
__global__ void gat_fused(const float* __restrict__ x,
                          const float* __restrict__ bl0, const float* __restrict__ br0,
                          const float* __restrict__ att0, const float* __restrict__ bias0,
                          const float* __restrict__ bl1, const float* __restrict__ br1,
                          const float* __restrict__ att1, const float* __restrict__ bias1,
                          const _Float16* __restrict__ wt,
                          float* __restrict__ out) {
    __shared__ _Float16 bufA[MR * 256];
    __shared__ _Float16 bufB[MR * 256];
    __shared__ float attbuf[2304];
    __shared__ _Float16 attH[768];

    const int tid  = threadIdx.x;
    const int bg   = blockIdx.x;
    const int lane = tid & 63;
    const int wv   = tid >> 6;
    const int lr   = lane & 15;
    const int lq   = lane >> 4;

    {
        const float4* src = (const float4*)(x + (size_t)bg * (MR * 256));
        #pragma unroll
        for (int it = 0; it < 4; ++it) {
            const int g   = it * 512 + tid;
            const int row = g >> 5;
            const int c   = g & 31;
            const float4 v0 = src[2 * g];
            const float4 v1 = src[2 * g + 1];
            f16x8 s;
            s[0] = (_Float16)fmaxf(v0.x, 0.f); s[1] = (_Float16)fmaxf(v0.y, 0.f);
            s[2] = (_Float16)fmaxf(v0.z, 0.f); s[3] = (_Float16)fmaxf(v0.w, 0.f);
            s[4] = (_Float16)fmaxf(v1.x, 0.f); s[5] = (_Float16)fmaxf(v1.y, 0.f);
            s[6] = (_Float16)fmaxf(v1.z, 0.f); s[7] = (_Float16)fmaxf(v1.w, 0.f);
            *(f16x8*)&bufA[swz(row, c)] = s;
        }
        if (tid < 256) {
            attH[tid]       = (_Float16)att0[tid];
            attH[512 + tid] = (_Float16)bias0[tid];
        } else {
            attH[tid]       = (_Float16)att1[tid - 256];
        }
    }
    __syncthreads();

    {
        f32x4 acc[4][4];
        #pragma unroll
        for (int m = 0; m < 4; ++m)
            #pragma unroll
            for (int n = 0; n < 4; ++n)
                acc[m][n] = f32x4{0.f, 0.f, 0.f, 0.f};
        #pragma unroll
        for (int kt = 0; kt < 8; ++kt) {
            f16x8 a[4], b[4];
            #pragma unroll
            for (int m = 0; m < 4; ++m)
                a[m] = *(const f16x8*)&bufA[swz(m * 16 + lr, kt * 4 + lq)];
            const int koff = kt * 32 + lq * 8;
            #pragma unroll
            for (int n = 0; n < 4; ++n)
                b[n] = *(const f16x8*)&wt[(size_t)(wv * 64 + n * 16 + lr) * 256 + koff];
            #pragma unroll
            for (int m = 0; m < 4; ++m)
                #pragma unroll
                for (int n = 0; n < 4; ++n)
                    acc[m][n] = __builtin_amdgcn_mfma_f32_16x16x32_f16(a[m], b[n], acc[m][n], 0, 0, 0);
        }
        __syncthreads();
        _Float16* dstbuf = (wv < 4) ? bufB : bufA;
        const float* bv = (wv < 4) ? bl0 : br0;
        #pragma unroll
        for (int n = 0; n < 4; ++n) {
            const int cl   = (wv & 3) * 64 + n * 16 + lr;
            const float bias = bv[cl];
            const int ch   = cl >> 3, ce = cl & 7;
            #pragma unroll
            for (int m = 0; m < 4; ++m)
                #pragma unroll
                for (int r = 0; r < 4; ++r) {
                    const int row = m * 16 + lq * 4 + r;
                    dstbuf[swz(row, ch) + ce] = (_Float16)(acc[m][n][r] + bias);
                }
        }
    }
    __syncthreads();

    {
        const int n  = tid >> 6;
        const int i  = (tid >> 3) & 7;
        const int h  = (tid >> 1) & 3;
        const int jh = tid & 1;
        const int rowR = n * 8 + i;
        f16x2 xr2[32];
        #pragma unroll
        for (int cc = 0; cc < 8; ++cc) {
            const int c3 = (cc + 2 * h) & 7;
            const f16x8 v = *(const f16x8*)&bufA[swz(rowR, h * 8 + c3)];
            xr2[cc * 4 + 0] = f16x2{v[0], v[1]};
            xr2[cc * 4 + 1] = f16x2{v[2], v[3]};
            xr2[cc * 4 + 2] = f16x2{v[4], v[5]};
            xr2[cc * 4 + 3] = f16x2{v[6], v[7]};
        }
        f16x8 lbuf[2][4];
        f16x8 abuf[2];
        {
            const int c3 = (2 * h) & 7;
            abuf[0] = *(const f16x8*)&attH[h * 64 + c3 * 8];
            #pragma unroll
            for (int jj = 0; jj < 4; ++jj)
                lbuf[0][jj] = *(const f16x8*)&bufB[swz(n * 8 + jh * 4 + jj, h * 8 + c3)];
        }
        float lg[4] = {0.f, 0.f, 0.f, 0.f};
        #pragma unroll
        for (int cc = 0; cc < 8; ++cc) {
            const int cur = cc & 1, nxt = cur ^ 1;
            if (cc < 7) {
                const int c3n = (cc + 1 + 2 * h) & 7;
                abuf[nxt] = *(const f16x8*)&attH[h * 64 + c3n * 8];
                #pragma unroll
                for (int jj = 0; jj < 4; ++jj)
                    lbuf[nxt][jj] = *(const f16x8*)&bufB[swz(n * 8 + jh * 4 + jj, h * 8 + c3n)];
            }
            const f16x8 a8 = abuf[cur];
            const f16x2 a2[4] = {{a8[0], a8[1]}, {a8[2], a8[3]}, {a8[4], a8[5]}, {a8[6], a8[7]}};
            #pragma unroll
            for (int jj = 0; jj < 4; ++jj) {
                const f16x8 l8 = lbuf[cur][jj];
                const f16x2 l2[4] = {{l8[0], l8[1]}, {l8[2], l8[3]}, {l8[4], l8[5]}, {l8[6], l8[7]}};
                #pragma unroll
                for (int p = 0; p < 4; ++p) {
                    const f16x2 t = leaky2(xr2[cc * 4 + p] + l2[p]);
                    lg[jj] = FDOT2(t, a2[p], lg[jj]);
                }
            }
        }
        float mx = fmaxf(fmaxf(lg[0], lg[1]), fmaxf(lg[2], lg[3]));
        mx = fmaxf(mx, __shfl_xor(mx, 1));
        float ex[4], ssum = 0.f;
        #pragma unroll
        for (int jj = 0; jj < 4; ++jj) { ex[jj] = __expf(lg[jj] - mx); ssum += ex[jj]; }
        const float tot = ssum + __shfl_xor(ssum, 1);
        const float inv = 1.f / tot;
        #pragma unroll
        for (int jj = 0; jj < 4; ++jj)
            attbuf[((n * 8 + i) * 4 + h) * 8 + jh * 4 + jj] = ex[jj] * inv;
    }
    __syncthreads();

    {
        const int row  = tid >> 3;
        const int sub  = tid & 7;
        const int h    = sub >> 1;
        const int half = sub & 1;
        const int nn   = row >> 3;
        const int cb   = h * 8 + half * 4;
        _Float16 ahv[8];
        #pragma unroll
        for (int j = 0; j < 8; ++j) ahv[j] = (_Float16)attbuf[(row * 4 + h) * 8 + j];
        f16x2 acc2[16];
        #pragma unroll
        for (int p = 0; p < 16; ++p) acc2[p] = (f16x2){(_Float16)0.f, (_Float16)0.f};
        f16x8 vbuf[2][4];
        #pragma unroll
        for (int cc = 0; cc < 4; ++cc)
            vbuf[0][cc] = *(const f16x8*)&bufB[swz(nn * 8, cb + ((cc + h) & 3))];
        #pragma unroll
        for (int j = 0; j < 8; ++j) {
            const int cur = j & 1, nxt = cur ^ 1;
            if (j < 7) {
                #pragma unroll
                for (int cc = 0; cc < 4; ++cc)
                    vbuf[nxt][cc] = *(const f16x8*)&bufB[swz(nn * 8 + j + 1, cb + ((cc + h) & 3))];
            }
            const f16x2 a2 = {ahv[j], ahv[j]};
            #pragma unroll
            for (int cc = 0; cc < 4; ++cc) {
                const f16x8 v = vbuf[cur][cc];
                acc2[cc * 4 + 0] += f16x2{v[0], v[1]} * a2;
                acc2[cc * 4 + 1] += f16x2{v[2], v[3]} * a2;
                acc2[cc * 4 + 2] += f16x2{v[4], v[5]} * a2;
                acc2[cc * 4 + 3] += f16x2{v[6], v[7]} * a2;
            }
        }
        #pragma unroll
        for (int cc = 0; cc < 4; ++cc) {
            const int c = cb + ((cc + h) & 3);
            const f16x8 b8 = *(const f16x8*)&attH[512 + c * 8];
            f16x8 s;
            #pragma unroll
            for (int p = 0; p < 4; ++p) {
                const f16x2 r = relu2(acc2[cc * 4 + p] + f16x2{b8[2 * p], b8[2 * p + 1]});
                s[2 * p]     = r[0];
                s[2 * p + 1] = r[1];
            }
            *(f16x8*)&bufA[swz(row, c)] = s;
        }
    }
    __syncthreads();

    {
        f32x4 accl[4][2], accr[2];
        #pragma unroll
        for (int m = 0; m < 4; ++m)
            #pragma unroll
            for (int n = 0; n < 2; ++n)
                accl[m][n] = f32x4{0.f, 0.f, 0.f, 0.f};
        #pragma unroll
        for (int n = 0; n < 2; ++n) accr[n] = f32x4{0.f, 0.f, 0.f, 0.f};
        const _Float16* W1l = wt + 512 * 256;
        const _Float16* W1r = wt + 768 * 256;
        const int rowS = (lr & 7) * 8 + 7;
        #pragma unroll
        for (int kt = 0; kt < 8; ++kt) {
            const int koff = kt * 32 + lq * 8;
            f16x8 a[4], as, bl[2], br[2];
            #pragma unroll
            for (int m = 0; m < 4; ++m)
                a[m] = *(const f16x8*)&bufA[swz(m * 16 + lr, kt * 4 + lq)];
            as = *(const f16x8*)&bufA[swz(rowS, kt * 4 + lq)];
            #pragma unroll
            for (int n = 0; n < 2; ++n) {
                bl[n] = *(const f16x8*)&W1l[(size_t)(wv * 32 + n * 16 + lr) * 256 + koff];
                br[n] = *(const f16x8*)&W1r[(size_t)(wv * 32 + n * 16 + lr) * 256 + koff];
            }
            #pragma unroll
            for (int m = 0; m < 4; ++m)
                #pragma unroll
                for (int n = 0; n < 2; ++n)
                    accl[m][n] = __builtin_amdgcn_mfma_f32_16x16x32_f16(a[m], bl[n], accl[m][n], 0, 0, 0);
            #pragma unroll
            for (int n = 0; n < 2; ++n)
                accr[n] = __builtin_amdgcn_mfma_f32_16x16x32_f16(as, br[n], accr[n], 0, 0, 0);
        }
        #pragma unroll
        for (int n = 0; n < 2; ++n) {
            const int col = wv * 32 + n * 16 + lr;
            const float b1 = bl1[col], b2 = br1[col];
            const int ch = col >> 3, ce = col & 7;
            #pragma unroll
            for (int m = 0; m < 4; ++m)
                #pragma unroll
                for (int r = 0; r < 4; ++r) {
                    const int row = m * 16 + lq * 4 + r;
                    bufB[swz(row, ch) + ce] = (_Float16)(accl[m][n][r] + b1);
                }
            if (lq < 2) {
                #pragma unroll
                for (int r = 0; r < 4; ++r) {
                    const int node = lq * 4 + r;
                    attbuf[node * 256 + col] = accr[n][r] + b2;
                }
            }
        }
    }
    __syncthreads();

    {
        const int n  = tid >> 5;
        const int rr = (tid >> 2) & 7;
        const int h  = tid & 3;
        float lg = 0.f;
        if (tid < 256) {
            const int rowj = n * 8 + rr;
            float4 xbuf0[2], xbuf1[2];
            f16x8 lbuf[2], abuf[2];
            {
                const int c = h * 8 + ((2 * h) & 7);
                xbuf0[0] = *(const float4*)&attbuf[n * 256 + c * 8];
                xbuf1[0] = *(const float4*)&attbuf[n * 256 + c * 8 + 4];
                lbuf[0]  = *(const f16x8*)&bufB[swz(rowj, c)];
                abuf[0]  = *(const f16x8*)&attH[256 + c * 8];
            }
            #pragma unroll
            for (int cc = 0; cc < 8; ++cc) {
                const int cur = cc & 1, nxt = cur ^ 1;
                if (cc < 7) {
                    const int cn = h * 8 + ((cc + 1 + 2 * h) & 7);
                    xbuf0[nxt] = *(const float4*)&attbuf[n * 256 + cn * 8];
                    xbuf1[nxt] = *(const float4*)&attbuf[n * 256 + cn * 8 + 4];
                    lbuf[nxt]  = *(const f16x8*)&bufB[swz(rowj, cn)];
                    abuf[nxt]  = *(const f16x8*)&attH[256 + cn * 8];
                }
                const float4 r0 = xbuf0[cur], r1 = xbuf1[cur];
                const f16x2 x2[4] = {pk2(r0.x, r0.y), pk2(r0.z, r0.w),
                                     pk2(r1.x, r1.y), pk2(r1.z, r1.w)};
                const f16x8 l8 = lbuf[cur];
                const f16x2 l2[4] = {{l8[0], l8[1]}, {l8[2], l8[3]}, {l8[4], l8[5]}, {l8[6], l8[7]}};
                const f16x8 a8 = abuf[cur];
                const f16x2 a2[4] = {{a8[0], a8[1]}, {a8[2], a8[3]}, {a8[4], a8[5]}, {a8[6], a8[7]}};
                #pragma unroll
                for (int p = 0; p < 4; ++p) {
                    const f16x2 t = leaky2(x2[p] + l2[p]);
                    lg = FDOT2(t, a2[p], lg);
                }
            }
        }
        __syncthreads();
        if (tid < 256) attbuf[2048 + tid] = lg;
        __syncthreads();
        if (tid < 256) {
            float M = -1e30f;
            float l[8];
            #pragma unroll
            for (int j = 0; j < 8; ++j) {
                l[j] = attbuf[2048 + n * 32 + j * 4 + h];
                M = fmaxf(M, l[j]);
            }
            float S = 0.f;
            #pragma unroll
            for (int j = 0; j < 8; ++j) S += __expf(l[j] - M);
            const float a = __expf(lg - M) / S;
            attbuf[tid] = a;
            out[(size_t)NNODES * 256 + (size_t)(bg * NB + n) * 32 + rr * 4 + h] = a;
        }
    }
    __syncthreads();

    {
        const int n  = tid >> 6;
        const int q  = tid & 63;
        const int c0 = q * 4;
        const int h  = q >> 4;
        f16x4 v[8];
        float a[8];
        #pragma unroll
        for (int r = 0; r < 8; ++r) {
            v[r] = *(const f16x4*)&bufB[swz(n * 8 + r, q >> 1) + (q & 1) * 4];
            a[r] = attbuf[n * 32 + r * 4 + h];
        }
        float o0 = 0.f, o1 = 0.f, o2 = 0.f, o3 = 0.f;
        #pragma unroll
        for (int r = 0; r < 8; ++r) {
            o0 = fmaf((float)v[r][0], a[r], o0);
            o1 = fmaf((float)v[r][1], a[r], o1);
            o2 = fmaf((float)v[r][2], a[r], o2);
            o3 = fmaf((float)v[r][3], a[r], o3);
        }
        float4 res;
        res.x = fmaxf(o0 + bias1[c0 + 0], 0.f);
        res.y = fmaxf(o1 + bias1[c0 + 1], 0.f);
        res.z = fmaxf(o2 + bias1[c0 + 2], 0.f);
        res.w = fmaxf(o3 + bias1[c0 + 3], 0.f);
        *(float4*)&out[(size_t)(bg * NB + n) * 256 + c0] = res;
    }
}

extern "C" void kernel_launch(void* const* d_in, const int* in_sizes, int n_in,
                              void* d_out, int out_size, void* d_ws, size_t ws_size,
                              hipStream_t stream) {
    const float* x     = (const float*)d_in[0];
    const float* Wl0   = (const float*)d_in[1];
    const float* bl0   = (const float*)d_in[2];
    const float* Wr0   = (const float*)d_in[3];
    const float* br0   = (const float*)d_in[4];
    const float* att0  = (const float*)d_in[5];
    const float* bias0 = (const float*)d_in[6];
    const float* Wl1   = (const float*)d_in[7];
    const float* bl1   = (const float*)d_in[8];
    const float* Wr1   = (const float*)d_in[9];
    const float* br1   = (const float*)d_in[10];
    const float* att1  = (const float*)d_in[11];
    const float* bias1 = (const float*)d_in[12];
    _Float16* wt = (_Float16*)d_ws;   // 512 KB
    float* out = (float*)d_out;

    prep_weights<<<64, 256, 0, stream>>>(Wl0, Wr0, Wl1, Wr1, wt);

    const size_t X1_off  = 524288;                              // wt region
    const size_t X1_size = (size_t)131072 * 512 * 2;            // 128 MiB f16
    if (ws_size >= X1_off + X1_size) {
        _Float16* X1 = (_Float16*)((char*)d_ws + X1_off);
        gemm0<<<4096, 512, 0, stream>>>(x, bl0, br0, wt, X1);
        gat_attn<<<NNODES / NB, 512, 0, stream>>>(att0, bias0, bl1, br1,
                                                  att1, bias1, wt, X1, out);
    } else {
        gat_fused<<<NNODES / NB, 512, 0, stream>>>(x, bl0, br0, att0, bias0,
                                                   bl1, br1, att1, bias1, wt, out);
    }
}

// Round 8
// 373.954 us; speedup vs baseline: 1.2244x; 1.1852x over previous
//
#include <hip/hip_runtime.h>

// MetapathGATConv for MI355X (gfx950) — R11.
// R10 decomposed the time (harness const ~145us): gemm0=195us, gat_attn~99us,
// prep~4us. gemm0 is clean (no spills, WRITE=131MB exactly) but latency-bound:
// FETCH 263MB (x re-read by 4 n-blocks), unprefetched b-loads, 64 MFMA/wave.
// Memory floor is ~42us. R11 rewrites gemm0 only: (1) one block per 128-row
// m-tile loops 4 n-quarters -> x read once; (2) wave=64x32 acc[4][2]=32 regs,
// b double-buffered across kt; (3) 16KB LDS bounce per 64-row half for
// coalesced X1 writes (layout unchanged -> gat_attn verbatim).
// Predicted: gemm0 195->65-85us, FETCH ~140MB, WRITE =131MB, bench ~305-325.

#define NNODES 16384
#define NB 8
#define MR 64              // rows per WG in attention kernel = NB*8

typedef _Float16 f16x8 __attribute__((ext_vector_type(8)));
typedef _Float16 f16x4 __attribute__((ext_vector_type(4)));
typedef _Float16 f16x2 __attribute__((ext_vector_type(2)));
typedef float f32x4 __attribute__((ext_vector_type(4)));

#if __has_builtin(__builtin_amdgcn_fdot2)
#define FDOT2(a, b, c) __builtin_amdgcn_fdot2((a), (b), (c), false)
#else
#define FDOT2(a, b, c) ((c) + (float)(a)[0] * (float)(b)[0] + (float)(a)[1] * (float)(b)[1])
#endif

__device__ __forceinline__ f16x2 pk2(float a, float b) {
    return __builtin_bit_cast(f16x2, __builtin_amdgcn_cvt_pkrtz(a, b));
}

__device__ __forceinline__ f16x2 leaky2(f16x2 t) {
#if __has_builtin(__builtin_elementwise_max)
    return __builtin_elementwise_max(t, t * (f16x2){(_Float16)0.2f, (_Float16)0.2f});
#else
    const unsigned u = __builtin_bit_cast(unsigned, t) & 0x7FFF7FFFu;
    const f16x2 at = __builtin_bit_cast(f16x2, u);
    return t * (f16x2){(_Float16)0.6f, (_Float16)0.6f} +
           at * (f16x2){(_Float16)0.4f, (_Float16)0.4f};
#endif
}
__device__ __forceinline__ f16x2 relu2(f16x2 t) {
#if __has_builtin(__builtin_elementwise_max)
    return __builtin_elementwise_max(t, (f16x2){(_Float16)0.f, (_Float16)0.f});
#else
    const unsigned u = __builtin_bit_cast(unsigned, t) & 0x7FFF7FFFu;
    const f16x2 at = __builtin_bit_cast(f16x2, u);
    return (t + at) * (f16x2){(_Float16)0.5f, (_Float16)0.5f};
#endif
}

// swizzled chunk address: buffers are [rows][32 chunks of 8 f16],
// chunk index XORed with (row&7) so column-strided accesses spread banks.
__device__ __forceinline__ int swz(int row, int chunk) {
    return row * 256 + ((chunk ^ (row & 7)) << 3);
}
// C-tile swizzle for gemm0 epilogue bounce: [rows][16 chunks of 8 f16].
__device__ __forceinline__ int cswz(int row, int col) {
    return row * 128 + (((col >> 3) ^ (row & 7)) << 3) + (col & 7);
}

// ---------------- weight prep: transpose+cast to f16 W^T[n][k] ----------------
// wt rows 0-255: Wl0^T | 256-511: Wr0^T | 512-767: Wl1^T | 768-1023: Wr1^T.
__global__ void prep_weights(const float* __restrict__ Wl0, const float* __restrict__ Wr0,
                             const float* __restrict__ Wl1, const float* __restrict__ Wr1,
                             _Float16* __restrict__ wt) {
    __shared__ float tile[64 * 68];   // 64x64 + pad 4
    const int t  = threadIdx.x;
    const int m  = blockIdx.x >> 4;
    const int kt = (blockIdx.x >> 2) & 3;
    const int nt = blockIdx.x & 3;
    const float* src = (m == 0 ? Wl0 : m == 1 ? Wr0 : m == 2 ? Wl1 : Wr1) + kt * 64 * 256;
    #pragma unroll
    for (int i = 0; i < 4; ++i) {
        const int idx = i * 256 + t;     // float4 id 0..1023
        const int kk  = idx >> 4;
        const int nn  = (idx & 15) * 4;
        const float4 v = *(const float4*)&src[kk * 256 + nt * 64 + nn];
        tile[kk * 68 + nn + 0] = v.x;
        tile[kk * 68 + nn + 1] = v.y;
        tile[kk * 68 + nn + 2] = v.z;
        tile[kk * 68 + nn + 3] = v.w;
    }
    __syncthreads();
    const int n  = t >> 2;
    const int ks = (t & 3) * 16;
    f16x8 o0, o1;
    #pragma unroll
    for (int e = 0; e < 8; ++e) o0[e] = (_Float16)tile[(ks + e) * 68 + n];
    #pragma unroll
    for (int e = 0; e < 8; ++e) o1[e] = (_Float16)tile[(ks + 8 + e) * 68 + n];
    _Float16* dst = &wt[(size_t)(m * 256 + nt * 64 + n) * 256 + kt * 64 + ks];
    *(f16x8*)dst = o0;
    *(f16x8*)(dst + 8) = o1;
}

// ---------------- K1: X1[131072][512] = relu(x) @ [Wl0|Wr0] + [bl0|br0] ----------------
// One block per 128-row m-tile (grid 1024); block loops 4 n-quarters of 128
// cols, reusing the staged A tile. Wave = 64 rows x 32 cols: acc[4][2]=32 acc
// regs, b[2][2] double-buffered across kt. Epilogue bounces each 64-row half
// through a 16KB LDS tile for coalesced f16x8 X1 stores.
__launch_bounds__(512, 4)
__global__ void gemm0(const float* __restrict__ x,
                      const float* __restrict__ bl0, const float* __restrict__ br0,
                      const _Float16* __restrict__ wt,
                      _Float16* __restrict__ X1) {
    __shared__ _Float16 A[128 * 256];   // 64 KB: relu(x) f16 tile (persists all quarters)
    __shared__ _Float16 Cb[64 * 128];   // 16 KB: C bounce (one 64-row half)
    const int mb   = blockIdx.x;
    const int row0 = mb * 128;
    const int tid  = threadIdx.x;
    const int lane = tid & 63;
    const int wv   = tid >> 6;          // 0..7
    const int lr   = lane & 15;
    const int lq   = lane >> 4;
    const int wr   = wv >> 2;           // 0..1: rows wr*64..+63
    const int wc   = wv & 3;            // 0..3: cols wc*32..+31 within quarter

    // stage A = f16(relu(x[row0..row0+127][:]))
    {
        const float4* src = (const float4*)(x + (size_t)row0 * 256);
        #pragma unroll
        for (int it = 0; it < 8; ++it) {
            const int g = it * 512 + tid;    // chunk id 0..4095: row=g>>5, c=g&31
            const int row = g >> 5, c = g & 31;
            const float4 v0 = src[2 * g];
            const float4 v1 = src[2 * g + 1];
            f16x8 s;
            s[0] = (_Float16)fmaxf(v0.x, 0.f); s[1] = (_Float16)fmaxf(v0.y, 0.f);
            s[2] = (_Float16)fmaxf(v0.z, 0.f); s[3] = (_Float16)fmaxf(v0.w, 0.f);
            s[4] = (_Float16)fmaxf(v1.x, 0.f); s[5] = (_Float16)fmaxf(v1.y, 0.f);
            s[6] = (_Float16)fmaxf(v1.z, 0.f); s[7] = (_Float16)fmaxf(v1.w, 0.f);
            *(f16x8*)&A[swz(row, c)] = s;
        }
    }
    __syncthreads();

    for (int nq = 0; nq < 4; ++nq) {
        f32x4 acc[4][2];
        #pragma unroll
        for (int m = 0; m < 4; ++m)
            #pragma unroll
            for (int n = 0; n < 2; ++n)
                acc[m][n] = f32x4{0.f, 0.f, 0.f, 0.f};
        const _Float16* wq = wt + (size_t)(nq * 128 + wc * 32) * 256;
        // b double-buffer: preload kt=0
        f16x8 b[2][2];
        b[0][0] = *(const f16x8*)&wq[(size_t)lr * 256 + lq * 8];
        b[0][1] = *(const f16x8*)&wq[(size_t)(16 + lr) * 256 + lq * 8];
        #pragma unroll
        for (int kt = 0; kt < 8; ++kt) {
            const int cur = kt & 1, nxt = cur ^ 1;
            if (kt < 7) {
                const int koff = (kt + 1) * 32 + lq * 8;
                b[nxt][0] = *(const f16x8*)&wq[(size_t)lr * 256 + koff];
                b[nxt][1] = *(const f16x8*)&wq[(size_t)(16 + lr) * 256 + koff];
            }
            f16x8 a[4];
            #pragma unroll
            for (int m = 0; m < 4; ++m)
                a[m] = *(const f16x8*)&A[swz(wr * 64 + m * 16 + lr, kt * 4 + lq)];
            #pragma unroll
            for (int m = 0; m < 4; ++m)
                #pragma unroll
                for (int n = 0; n < 2; ++n)
                    acc[m][n] = __builtin_amdgcn_mfma_f32_16x16x32_f16(a[m], b[cur][n], acc[m][n], 0, 0, 0);
        }
        // epilogue: two 64-row halves through Cb (coalesced X1 stores)
        #pragma unroll
        for (int mh = 0; mh < 2; ++mh) {
            __syncthreads();   // Cb free (previous copy / previous quarter done)
            if (wr == mh) {
                #pragma unroll
                for (int n = 0; n < 2; ++n) {
                    const int col  = wc * 32 + n * 16 + lr;   // 0..127 within quarter
                    const int gcol = nq * 128 + col;          // 0..511
                    const float bias = (gcol < 256) ? bl0[gcol] : br0[gcol - 256];
                    #pragma unroll
                    for (int m = 0; m < 4; ++m)
                        #pragma unroll
                        for (int r = 0; r < 4; ++r) {
                            const int row = m * 16 + lq * 4 + r;   // 0..63 within half
                            Cb[cswz(row, col)] = (_Float16)(acc[m][n][r] + bias);
                        }
                }
            }
            __syncthreads();
            // copy 64x128 f16 (1024 chunks of 16B) to X1, coalesced
            #pragma unroll
            for (int it = 0; it < 2; ++it) {
                const int g = it * 512 + tid;    // row = g>>4 (0..63), ch = g&15
                const int row = g >> 4, ch = g & 15;
                const f16x8 v = *(const f16x8*)&Cb[row * 128 + ((ch ^ (row & 7)) << 3)];
                *(f16x8*)&X1[(size_t)(row0 + mh * 64 + row) * 512 + nq * 128 + ch * 8] = v;
            }
        }
    }
}

// ---------------- K2: attention chain (R4's P2..P7 verbatim; stage from X1) ----------------
__launch_bounds__(512, 4)
__global__ void gat_attn(const float* __restrict__ att0, const float* __restrict__ bias0,
                         const float* __restrict__ bl1, const float* __restrict__ br1,
                         const float* __restrict__ att1, const float* __restrict__ bias1,
                         const _Float16* __restrict__ wt,
                         const _Float16* __restrict__ X1,
                         float* __restrict__ out) {
    __shared__ _Float16 bufA[MR * 256];  // 32 KB: xr0 -> h1
    __shared__ _Float16 bufB[MR * 256];  // 32 KB: xl0 -> xl1
    __shared__ float attbuf[2304];       // 9 KB
    __shared__ _Float16 attH[768];       // 1.5 KB

    const int tid  = threadIdx.x;
    const int bg   = blockIdx.x;
    const int lane = tid & 63;
    const int wv   = tid >> 6;
    const int lr   = lane & 15;
    const int lq   = lane >> 4;

    // stage: bufB = xl0 rows, bufA = xr0 rows (from X1), attH consts
    {
        const _Float16* src = X1 + (size_t)bg * 64 * 512;
        #pragma unroll
        for (int it = 0; it < 4; ++it) {
            const int g = it * 512 + tid;   // 0..2047: row = g>>5, c = g&31
            const int row = g >> 5, c = g & 31;
            const f16x8 vl = *(const f16x8*)&src[(size_t)row * 512 + c * 8];
            const f16x8 vr = *(const f16x8*)&src[(size_t)row * 512 + 256 + c * 8];
            *(f16x8*)&bufB[swz(row, c)] = vl;
            *(f16x8*)&bufA[swz(row, c)] = vr;
        }
        if (tid < 256) {
            attH[tid]       = (_Float16)att0[tid];
            attH[512 + tid] = (_Float16)bias0[tid];
        } else {
            attH[tid]       = (_Float16)att1[tid - 256];
        }
    }
    __syncthreads();

    // ---------------- P2: layer-0 logits + softmax over j -> alpha0 ----------------
    {
        const int n  = tid >> 6;
        const int i  = (tid >> 3) & 7;
        const int h  = (tid >> 1) & 3;
        const int jh = tid & 1;
        const int rowR = n * 8 + i;
        f16x2 xr2[32];
        #pragma unroll
        for (int cc = 0; cc < 8; ++cc) {
            const int c3 = (cc + 2 * h) & 7;
            const f16x8 v = *(const f16x8*)&bufA[swz(rowR, h * 8 + c3)];
            xr2[cc * 4 + 0] = f16x2{v[0], v[1]};
            xr2[cc * 4 + 1] = f16x2{v[2], v[3]};
            xr2[cc * 4 + 2] = f16x2{v[4], v[5]};
            xr2[cc * 4 + 3] = f16x2{v[6], v[7]};
        }
        f16x8 lbuf[2][4];
        f16x8 abuf[2];
        {
            const int c3 = (2 * h) & 7;
            abuf[0] = *(const f16x8*)&attH[h * 64 + c3 * 8];
            #pragma unroll
            for (int jj = 0; jj < 4; ++jj)
                lbuf[0][jj] = *(const f16x8*)&bufB[swz(n * 8 + jh * 4 + jj, h * 8 + c3)];
        }
        float lg[4] = {0.f, 0.f, 0.f, 0.f};
        #pragma unroll
        for (int cc = 0; cc < 8; ++cc) {
            const int cur = cc & 1, nxt = cur ^ 1;
            if (cc < 7) {
                const int c3n = (cc + 1 + 2 * h) & 7;
                abuf[nxt] = *(const f16x8*)&attH[h * 64 + c3n * 8];
                #pragma unroll
                for (int jj = 0; jj < 4; ++jj)
                    lbuf[nxt][jj] = *(const f16x8*)&bufB[swz(n * 8 + jh * 4 + jj, h * 8 + c3n)];
            }
            const f16x8 a8 = abuf[cur];
            const f16x2 a2[4] = {{a8[0], a8[1]}, {a8[2], a8[3]}, {a8[4], a8[5]}, {a8[6], a8[7]}};
            #pragma unroll
            for (int jj = 0; jj < 4; ++jj) {
                const f16x8 l8 = lbuf[cur][jj];
                const f16x2 l2[4] = {{l8[0], l8[1]}, {l8[2], l8[3]}, {l8[4], l8[5]}, {l8[6], l8[7]}};
                #pragma unroll
                for (int p = 0; p < 4; ++p) {
                    const f16x2 t = leaky2(xr2[cc * 4 + p] + l2[p]);
                    lg[jj] = FDOT2(t, a2[p], lg[jj]);
                }
            }
        }
        float mx = fmaxf(fmaxf(lg[0], lg[1]), fmaxf(lg[2], lg[3]));
        mx = fmaxf(mx, __shfl_xor(mx, 1));
        float ex[4], ssum = 0.f;
        #pragma unroll
        for (int jj = 0; jj < 4; ++jj) { ex[jj] = __expf(lg[jj] - mx); ssum += ex[jj]; }
        const float tot = ssum + __shfl_xor(ssum, 1);
        const float inv = 1.f / tot;
        #pragma unroll
        for (int jj = 0; jj < 4; ++jj)
            attbuf[((n * 8 + i) * 4 + h) * 8 + jh * 4 + jj] = ex[jj] * inv;
    }
    __syncthreads();

    // ---------------- P3: h1 = relu(alpha0 @ xl0 + bias0) -> bufA ----------------
    {
        const int row  = tid >> 3;
        const int sub  = tid & 7;
        const int h    = sub >> 1;
        const int half = sub & 1;
        const int nn   = row >> 3;
        const int cb   = h * 8 + half * 4;
        _Float16 ahv[8];
        #pragma unroll
        for (int j = 0; j < 8; ++j) ahv[j] = (_Float16)attbuf[(row * 4 + h) * 8 + j];
        f16x2 acc2[16];
        #pragma unroll
        for (int p = 0; p < 16; ++p) acc2[p] = (f16x2){(_Float16)0.f, (_Float16)0.f};
        f16x8 vbuf[2][4];
        #pragma unroll
        for (int cc = 0; cc < 4; ++cc)
            vbuf[0][cc] = *(const f16x8*)&bufB[swz(nn * 8, cb + ((cc + h) & 3))];
        #pragma unroll
        for (int j = 0; j < 8; ++j) {
            const int cur = j & 1, nxt = cur ^ 1;
            if (j < 7) {
                #pragma unroll
                for (int cc = 0; cc < 4; ++cc)
                    vbuf[nxt][cc] = *(const f16x8*)&bufB[swz(nn * 8 + j + 1, cb + ((cc + h) & 3))];
            }
            const f16x2 a2 = {ahv[j], ahv[j]};
            #pragma unroll
            for (int cc = 0; cc < 4; ++cc) {
                const f16x8 v = vbuf[cur][cc];
                acc2[cc * 4 + 0] += f16x2{v[0], v[1]} * a2;
                acc2[cc * 4 + 1] += f16x2{v[2], v[3]} * a2;
                acc2[cc * 4 + 2] += f16x2{v[4], v[5]} * a2;
                acc2[cc * 4 + 3] += f16x2{v[6], v[7]} * a2;
            }
        }
        #pragma unroll
        for (int cc = 0; cc < 4; ++cc) {
            const int c = cb + ((cc + h) & 3);
            const f16x8 b8 = *(const f16x8*)&attH[512 + c * 8];
            f16x8 s;
            #pragma unroll
            for (int p = 0; p < 4; ++p) {
                const f16x2 r = relu2(acc2[cc * 4 + p] + f16x2{b8[2 * p], b8[2 * p + 1]});
                s[2 * p]     = r[0];
                s[2 * p + 1] = r[1];
            }
            *(f16x8*)&bufA[swz(row, c)] = s;
        }
    }
    __syncthreads();

    // ---------------- P5: GEMM1: xl1 -> bufB ; xrs -> attbuf ----------------
    {
        f32x4 accl[4][2], accr[2];
        #pragma unroll
        for (int m = 0; m < 4; ++m)
            #pragma unroll
            for (int n = 0; n < 2; ++n)
                accl[m][n] = f32x4{0.f, 0.f, 0.f, 0.f};
        #pragma unroll
        for (int n = 0; n < 2; ++n) accr[n] = f32x4{0.f, 0.f, 0.f, 0.f};
        const _Float16* W1l = wt + 512 * 256;
        const _Float16* W1r = wt + 768 * 256;
        const int rowS = (lr & 7) * 8 + 7;
        #pragma unroll
        for (int kt = 0; kt < 8; ++kt) {
            const int koff = kt * 32 + lq * 8;
            f16x8 a[4], as, bl[2], br[2];
            #pragma unroll
            for (int m = 0; m < 4; ++m)
                a[m] = *(const f16x8*)&bufA[swz(m * 16 + lr, kt * 4 + lq)];
            as = *(const f16x8*)&bufA[swz(rowS, kt * 4 + lq)];
            #pragma unroll
            for (int n = 0; n < 2; ++n) {
                bl[n] = *(const f16x8*)&W1l[(size_t)(wv * 32 + n * 16 + lr) * 256 + koff];
                br[n] = *(const f16x8*)&W1r[(size_t)(wv * 32 + n * 16 + lr) * 256 + koff];
            }
            #pragma unroll
            for (int m = 0; m < 4; ++m)
                #pragma unroll
                for (int n = 0; n < 2; ++n)
                    accl[m][n] = __builtin_amdgcn_mfma_f32_16x16x32_f16(a[m], bl[n], accl[m][n], 0, 0, 0);
            #pragma unroll
            for (int n = 0; n < 2; ++n)
                accr[n] = __builtin_amdgcn_mfma_f32_16x16x32_f16(as, br[n], accr[n], 0, 0, 0);
        }
        #pragma unroll
        for (int n = 0; n < 2; ++n) {
            const int col = wv * 32 + n * 16 + lr;
            const float b1 = bl1[col], b2 = br1[col];
            const int ch = col >> 3, ce = col & 7;
            #pragma unroll
            for (int m = 0; m < 4; ++m)
                #pragma unroll
                for (int r = 0; r < 4; ++r) {
                    const int row = m * 16 + lq * 4 + r;
                    bufB[swz(row, ch) + ce] = (_Float16)(accl[m][n][r] + b1);
                }
            if (lq < 2) {
                #pragma unroll
                for (int r = 0; r < 4; ++r) {
                    const int node = lq * 4 + r;
                    attbuf[node * 256 + col] = accr[n][r] + b2;
                }
            }
        }
    }
    __syncthreads();

    // ---------------- P6: layer-1 logits, softmax over r -> betas + alpha1 ----------------
    {
        const int n  = tid >> 5;
        const int rr = (tid >> 2) & 7;
        const int h  = tid & 3;
        float lg = 0.f;
        if (tid < 256) {
            const int rowj = n * 8 + rr;
            float4 xbuf0[2], xbuf1[2];
            f16x8 lbuf[2], abuf[2];
            {
                const int c = h * 8 + ((2 * h) & 7);
                xbuf0[0] = *(const float4*)&attbuf[n * 256 + c * 8];
                xbuf1[0] = *(const float4*)&attbuf[n * 256 + c * 8 + 4];
                lbuf[0]  = *(const f16x8*)&bufB[swz(rowj, c)];
                abuf[0]  = *(const f16x8*)&attH[256 + c * 8];
            }
            #pragma unroll
            for (int cc = 0; cc < 8; ++cc) {
                const int cur = cc & 1, nxt = cur ^ 1;
                if (cc < 7) {
                    const int cn = h * 8 + ((cc + 1 + 2 * h) & 7);
                    xbuf0[nxt] = *(const float4*)&attbuf[n * 256 + cn * 8];
                    xbuf1[nxt] = *(const float4*)&attbuf[n * 256 + cn * 8 + 4];
                    lbuf[nxt]  = *(const f16x8*)&bufB[swz(rowj, cn)];
                    abuf[nxt]  = *(const f16x8*)&attH[256 + cn * 8];
                }
                const float4 r0 = xbuf0[cur], r1 = xbuf1[cur];
                const f16x2 x2[4] = {pk2(r0.x, r0.y), pk2(r0.z, r0.w),
                                     pk2(r1.x, r1.y), pk2(r1.z, r1.w)};
                const f16x8 l8 = lbuf[cur];
                const f16x2 l2[4] = {{l8[0], l8[1]}, {l8[2], l8[3]}, {l8[4], l8[5]}, {l8[6], l8[7]}};
                const f16x8 a8 = abuf[cur];
                const f16x2 a2[4] = {{a8[0], a8[1]}, {a8[2], a8[3]}, {a8[4], a8[5]}, {a8[6], a8[7]}};
                #pragma unroll
                for (int p = 0; p < 4; ++p) {
                    const f16x2 t = leaky2(x2[p] + l2[p]);
                    lg = FDOT2(t, a2[p], lg);
                }
            }
        }
        __syncthreads();
        if (tid < 256) attbuf[2048 + tid] = lg;
        __syncthreads();
        if (tid < 256) {
            float M = -1e30f;
            float l[8];
            #pragma unroll
            for (int j = 0; j < 8; ++j) {
                l[j] = attbuf[2048 + n * 32 + j * 4 + h];
                M = fmaxf(M, l[j]);
            }
            float S = 0.f;
            #pragma unroll
            for (int j = 0; j < 8; ++j) S += __expf(l[j] - M);
            const float a = __expf(lg - M) / S;
            attbuf[tid] = a;
            out[(size_t)NNODES * 256 + (size_t)(bg * NB + n) * 32 + rr * 4 + h] = a;
        }
    }
    __syncthreads();

    // ---------------- P7: out = relu(alpha1 @ xl1 + bias1) ----------------
    {
        const int n  = tid >> 6;
        const int q  = tid & 63;
        const int c0 = q * 4;
        const int h  = q >> 4;
        f16x4 v[8];
        float a[8];
        #pragma unroll
        for (int r = 0; r < 8; ++r) {
            v[r] = *(const f16x4*)&bufB[swz(n * 8 + r, q >> 1) + (q & 1) * 4];
            a[r] = attbuf[n * 32 + r * 4 + h];
        }
        float o0 = 0.f, o1 = 0.f, o2 = 0.f, o3 = 0.f;
        #pragma unroll
        for (int r = 0; r < 8; ++r) {
            o0 = fmaf((float)v[r][0], a[r], o0);
            o1 = fmaf((float)v[r][1], a[r], o1);
            o2 = fmaf((float)v[r][2], a[r], o2);
            o3 = fmaf((float)v[r][3], a[r], o3);
        }
        float4 res;
        res.x = fmaxf(o0 + bias1[c0 + 0], 0.f);
        res.y = fmaxf(o1 + bias1[c0 + 1], 0.f);
        res.z = fmaxf(o2 + bias1[c0 + 2], 0.f);
        res.w = fmaxf(o3 + bias1[c0 + 3], 0.f);
        *(float4*)&out[(size_t)(bg * NB + n) * 256 + c0] = res;
    }
}

// ---------------- Fallback: R4 fused kernel, verbatim (201us proven) ----------------
__launch_bounds__(512, 4)
__global__ void gat_fused(const float* __restrict__ x,
                          const float* __restrict__ bl0, const float* __restrict__ br0,
                          const float* __restrict__ att0, const float* __restrict__ bias0,
                          const float* __restrict__ bl1, const float* __restrict__ br1,
                          const float* __restrict__ att1, const float* __restrict__ bias1,
                          const _Float16* __restrict__ wt,
                          float* __restrict__ out) {
    __shared__ _Float16 bufA[MR * 256];
    __shared__ _Float16 bufB[MR * 256];
    __shared__ float attbuf[2304];
    __shared__ _Float16 attH[768];

    const int tid  = threadIdx.x;
    const int bg   = blockIdx.x;
    const int lane = tid & 63;
    const int wv   = tid >> 6;
    const int lr   = lane & 15;
    const int lq   = lane >> 4;

    {
        const float4* src = (const float4*)(x + (size_t)bg * (MR * 256));
        #pragma unroll
        for (int it = 0; it < 4; ++it) {
            const int g   = it * 512 + tid;
            const int row = g >> 5;
            const int c   = g & 31;
            const float4 v0 = src[2 * g];
            const float4 v1 = src[2 * g + 1];
            f16x8 s;
            s[0] = (_Float16)fmaxf(v0.x, 0.f); s[1] = (_Float16)fmaxf(v0.y, 0.f);
            s[2] = (_Float16)fmaxf(v0.z, 0.f); s[3] = (_Float16)fmaxf(v0.w, 0.f);
            s[4] = (_Float16)fmaxf(v1.x, 0.f); s[5] = (_Float16)fmaxf(v1.y, 0.f);
            s[6] = (_Float16)fmaxf(v1.z, 0.f); s[7] = (_Float16)fmaxf(v1.w, 0.f);
            *(f16x8*)&bufA[swz(row, c)] = s;
        }
        if (tid < 256) {
            attH[tid]       = (_Float16)att0[tid];
            attH[512 + tid] = (_Float16)bias0[tid];
        } else {
            attH[tid]       = (_Float16)att1[tid - 256];
        }
    }
    __syncthreads();

    {
        f32x4 acc[4][4];
        #pragma unroll
        for (int m = 0; m < 4; ++m)
            #pragma unroll
            for (int n = 0; n < 4; ++n)
                acc[m][n] = f32x4{0.f, 0.f, 0.f, 0.f};
        #pragma unroll
        for (int kt = 0; kt < 8; ++kt) {
            f16x8 a[4], b[4];
            #pragma unroll
            for (int m = 0; m < 4; ++m)
                a[m] = *(const f16x8*)&bufA[swz(m * 16 + lr, kt * 4 + lq)];
            const int koff = kt * 32 + lq * 8;
            #pragma unroll
            for (int n = 0; n < 4; ++n)
                b[n] = *(const f16x8*)&wt[(size_t)(wv * 64 + n * 16 + lr) * 256 + koff];
            #pragma unroll
            for (int m = 0; m < 4; ++m)
                #pragma unroll
                for (int n = 0; n < 4; ++n)
                    acc[m][n] = __builtin_amdgcn_mfma_f32_16x16x32_f16(a[m], b[n], acc[m][n], 0, 0, 0);
        }
        __syncthreads();
        _Float16* dstbuf = (wv < 4) ? bufB : bufA;
        const float* bv = (wv < 4) ? bl0 : br0;
        #pragma unroll
        for (int n = 0; n < 4; ++n) {
            const int cl   = (wv & 3) * 64 + n * 16 + lr;
            const float bias = bv[cl];
            const int ch   = cl >> 3, ce = cl & 7;
            #pragma unroll
            for (int m = 0; m < 4; ++m)
                #pragma unroll
                for (int r = 0; r < 4; ++r) {
                    const int row = m * 16 + lq * 4 + r;
                    dstbuf[swz(row, ch) + ce] = (_Float16)(acc[m][n][r] + bias);
                }
        }
    }
    __syncthreads();

    {
        const int n  = tid >> 6;
        const int i  = (tid >> 3) & 7;
        const int h  = (tid >> 1) & 3;
        const int jh = tid & 1;
        const int rowR = n * 8 + i;
        f16x2 xr2[32];
        #pragma unroll
        for (int cc = 0; cc < 8; ++cc) {
            const int c3 = (cc + 2 * h) & 7;
            const f16x8 v = *(const f16x8*)&bufA[swz(rowR, h * 8 + c3)];
            xr2[cc * 4 + 0] = f16x2{v[0], v[1]};
            xr2[cc * 4 + 1] = f16x2{v[2], v[3]};
            xr2[cc * 4 + 2] = f16x2{v[4], v[5]};
            xr2[cc * 4 + 3] = f16x2{v[6], v[7]};
        }
        f16x8 lbuf[2][4];
        f16x8 abuf[2];
        {
            const int c3 = (2 * h) & 7;
            abuf[0] = *(const f16x8*)&attH[h * 64 + c3 * 8];
            #pragma unroll
            for (int jj = 0; jj < 4; ++jj)
                lbuf[0][jj] = *(const f16x8*)&bufB[swz(n * 8 + jh * 4 + jj, h * 8 + c3)];
        }
        float lg[4] = {0.f, 0.f, 0.f, 0.f};
        #pragma unroll
        for (int cc = 0; cc < 8; ++cc) {
            const int cur = cc & 1, nxt = cur ^ 1;
            if (cc < 7) {
                const int c3n = (cc + 1 + 2 * h) & 7;
                abuf[nxt] = *(const f16x8*)&attH[h * 64 + c3n * 8];
                #pragma unroll
                for (int jj = 0; jj < 4; ++jj)
                    lbuf[nxt][jj] = *(const f16x8*)&bufB[swz(n * 8 + jh * 4 + jj, h * 8 + c3n)];
            }
            const f16x8 a8 = abuf[cur];
            const f16x2 a2[4] = {{a8[0], a8[1]}, {a8[2], a8[3]}, {a8[4], a8[5]}, {a8[6], a8[7]}};
            #pragma unroll
            for (int jj = 0; jj < 4; ++jj) {
                const f16x8 l8 = lbuf[cur][jj];
                const f16x2 l2[4] = {{l8[0], l8[1]}, {l8[2], l8[3]}, {l8[4], l8[5]}, {l8[6], l8[7]}};
                #pragma unroll
                for (int p = 0; p < 4; ++p) {
                    const f16x2 t = leaky2(xr2[cc * 4 + p] + l2[p]);
                    lg[jj] = FDOT2(t, a2[p], lg[jj]);
                }
            }
        }
        float mx = fmaxf(fmaxf(lg[0], lg[1]), fmaxf(lg[2], lg[3]));
        mx = fmaxf(mx, __shfl_xor(mx, 1));
        float ex[4], ssum = 0.f;
        #pragma unroll
        for (int jj = 0; jj < 4; ++jj) { ex[jj] = __expf(lg[jj] - mx); ssum += ex[jj]; }
        const float tot = ssum + __shfl_xor(ssum, 1);
        const float inv = 1.f / tot;
        #pragma unroll
        for (int jj = 0; jj < 4; ++jj)
            attbuf[((n * 8 + i) * 4 + h) * 8 + jh * 4 + jj] = ex[jj] * inv;
    }
    __syncthreads();

    {
        const int row  = tid >> 3;
        const int sub  = tid & 7;
        const int h    = sub >> 1;
        const int half = sub & 1;
        const int nn   = row >> 3;
        const int cb   = h * 8 + half * 4;
        _Float16 ahv[8];
        #pragma unroll
        for (int j = 0; j < 8; ++j) ahv[j] = (_Float16)attbuf[(row * 4 + h) * 8 + j];
        f16x2 acc2[16];
        #pragma unroll
        for (int p = 0; p < 16; ++p) acc2[p] = (f16x2){(_Float16)0.f, (_Float16)0.f};
        f16x8 vbuf[2][4];
        #pragma unroll
        for (int cc = 0; cc < 4; ++cc)
            vbuf[0][cc] = *(const f16x8*)&bufB[swz(nn * 8, cb + ((cc + h) & 3))];
        #pragma unroll
        for (int j = 0; j < 8; ++j) {
            const int cur = j & 1, nxt = cur ^ 1;
            if (j < 7) {
                #pragma unroll
                for (int cc = 0; cc < 4; ++cc)
                    vbuf[nxt][cc] = *(const f16x8*)&bufB[swz(nn * 8 + j + 1, cb + ((cc + h) & 3))];
            }
            const f16x2 a2 = {ahv[j], ahv[j]};
            #pragma unroll
            for (int cc = 0; cc < 4; ++cc) {
                const f16x8 v = vbuf[cur][cc];
                acc2[cc * 4 + 0] += f16x2{v[0], v[1]} * a2;
                acc2[cc * 4 + 1] += f16x2{v[2], v[3]} * a2;
                acc2[cc * 4 + 2] += f16x2{v[4], v[5]} * a2;
                acc2[cc * 4 + 3] += f16x2{v[6], v[7]} * a2;
            }
        }
        #pragma unroll
        for (int cc = 0; cc < 4; ++cc) {
            const int c = cb + ((cc + h) & 3);
            const f16x8 b8 = *(const f16x8*)&attH[512 + c * 8];
            f16x8 s;
            #pragma unroll
            for (int p = 0; p < 4; ++p) {
                const f16x2 r = relu2(acc2[cc * 4 + p] + f16x2{b8[2 * p], b8[2 * p + 1]});
                s[2 * p]     = r[0];
                s[2 * p + 1] = r[1];
            }
            *(f16x8*)&bufA[swz(row, c)] = s;
        }
    }
    __syncthreads();

    {
        f32x4 accl[4][2], accr[2];
        #pragma unroll
        for (int m = 0; m < 4; ++m)
            #pragma unroll
            for (int n = 0; n < 2; ++n)
                accl[m][n] = f32x4{0.f, 0.f, 0.f, 0.f};
        #pragma unroll
        for (int n = 0; n < 2; ++n) accr[n] = f32x4{0.f, 0.f, 0.f, 0.f};
        const _Float16* W1l = wt + 512 * 256;
        const _Float16* W1r = wt + 768 * 256;
        const int rowS = (lr & 7) * 8 + 7;
        #pragma unroll
        for (int kt = 0; kt < 8; ++kt) {
            const int koff = kt * 32 + lq * 8;
            f16x8 a[4], as, bl[2], br[2];
            #pragma unroll
            for (int m = 0; m < 4; ++m)
                a[m] = *(const f16x8*)&bufA[swz(m * 16 + lr, kt * 4 + lq)];
            as = *(const f16x8*)&bufA[swz(rowS, kt * 4 + lq)];
            #pragma unroll
            for (int n = 0; n < 2; ++n) {
                bl[n] = *(const f16x8*)&W1l[(size_t)(wv * 32 + n * 16 + lr) * 256 + koff];
                br[n] = *(const f16x8*)&W1r[(size_t)(wv * 32 + n * 16 + lr) * 256 + koff];
            }
            #pragma unroll
            for (int m = 0; m < 4; ++m)
                #pragma unroll
                for (int n = 0; n < 2; ++n)
                    accl[m][n] = __builtin_amdgcn_mfma_f32_16x16x32_f16(a[m], bl[n], accl[m][n], 0, 0, 0);
            #pragma unroll
            for (int n = 0; n < 2; ++n)
                accr[n] = __builtin_amdgcn_mfma_f32_16x16x32_f16(as, br[n], accr[n], 0, 0, 0);
        }
        #pragma unroll
        for (int n = 0; n < 2; ++n) {
            const int col = wv * 32 + n * 16 + lr;
            const float b1 = bl1[col], b2 = br1[col];
            const int ch = col >> 3, ce = col & 7;
            #pragma unroll
            for (int m = 0; m < 4; ++m)
                #pragma unroll
                for (int r = 0; r < 4; ++r) {
                    const int row = m * 16 + lq * 4 + r;
                    bufB[swz(row, ch) + ce] = (_Float16)(accl[m][n][r] + b1);
                }
            if (lq < 2) {
                #pragma unroll
                for (int r = 0; r < 4; ++r) {
                    const int node = lq * 4 + r;
                    attbuf[node * 256 + col] = accr[n][r] + b2;
                }
            }
        }
    }
    __syncthreads();

    {
        const int n  = tid >> 5;
        const int rr = (tid >> 2) & 7;
        const int h  = tid & 3;
        float lg = 0.f;
        if (tid < 256) {
            const int rowj = n * 8 + rr;
            float4 xbuf0[2], xbuf1[2];
            f16x8 lbuf[2], abuf[2];
            {
                const int c = h * 8 + ((2 * h) & 7);
                xbuf0[0] = *(const float4*)&attbuf[n * 256 + c * 8];
                xbuf1[0] = *(const float4*)&attbuf[n * 256 + c * 8 + 4];
                lbuf[0]  = *(const f16x8*)&bufB[swz(rowj, c)];
                abuf[0]  = *(const f16x8*)&attH[256 + c * 8];
            }
            #pragma unroll
            for (int cc = 0; cc < 8; ++cc) {
                const int cur = cc & 1, nxt = cur ^ 1;
                if (cc < 7) {
                    const int cn = h * 8 + ((cc + 1 + 2 * h) & 7);
                    xbuf0[nxt] = *(const float4*)&attbuf[n * 256 + cn * 8];
                    xbuf1[nxt] = *(const float4*)&attbuf[n * 256 + cn * 8 + 4];
                    lbuf[nxt]  = *(const f16x8*)&bufB[swz(rowj, cn)];
                    abuf[nxt]  = *(const f16x8*)&attH[256 + cn * 8];
                }
                const float4 r0 = xbuf0[cur], r1 = xbuf1[cur];
                const f16x2 x2[4] = {pk2(r0.x, r0.y), pk2(r0.z, r0.w),
                                     pk2(r1.x, r1.y), pk2(r1.z, r1.w)};
                const f16x8 l8 = lbuf[cur];
                const f16x2 l2[4] = {{l8[0], l8[1]}, {l8[2], l8[3]}, {l8[4], l8[5]}, {l8[6], l8[7]}};
                const f16x8 a8 = abuf[cur];
                const f16x2 a2[4] = {{a8[0], a8[1]}, {a8[2], a8[3]}, {a8[4], a8[5]}, {a8[6], a8[7]}};
                #pragma unroll
                for (int p = 0; p < 4; ++p) {
                    const f16x2 t = leaky2(x2[p] + l2[p]);
                    lg = FDOT2(t, a2[p], lg);
                }
            }
        }
        __syncthreads();
        if (tid < 256) attbuf[2048 + tid] = lg;
        __syncthreads();
        if (tid < 256) {
            float M = -1e30f;
            float l[8];
            #pragma unroll
            for (int j = 0; j < 8; ++j) {
                l[j] = attbuf[2048 + n * 32 + j * 4 + h];
                M = fmaxf(M, l[j]);
            }
            float S = 0.f;
            #pragma unroll
            for (int j = 0; j < 8; ++j) S += __expf(l[j] - M);
            const float a = __expf(lg - M) / S;
            attbuf[tid] = a;
            out[(size_t)NNODES * 256 + (size_t)(bg * NB + n) * 32 + rr * 4 + h] = a;
        }
    }
    __syncthreads();

    {
        const int n  = tid >> 6;
        const int q  = tid & 63;
        const int c0 = q * 4;
        const int h  = q >> 4;
        f16x4 v[8];
        float a[8];
        #pragma unroll
        for (int r = 0; r < 8; ++r) {
            v[r] = *(const f16x4*)&bufB[swz(n * 8 + r, q >> 1) + (q & 1) * 4];
            a[r] = attbuf[n * 32 + r * 4 + h];
        }
        float o0 = 0.f, o1 = 0.f, o2 = 0.f, o3 = 0.f;
        #pragma unroll
        for (int r = 0; r < 8; ++r) {
            o0 = fmaf((float)v[r][0], a[r], o0);
            o1 = fmaf((float)v[r][1], a[r], o1);
            o2 = fmaf((float)v[r][2], a[r], o2);
            o3 = fmaf((float)v[r][3], a[r], o3);
        }
        float4 res;
        res.x = fmaxf(o0 + bias1[c0 + 0], 0.f);
        res.y = fmaxf(o1 + bias1[c0 + 1], 0.f);
        res.z = fmaxf(o2 + bias1[c0 + 2], 0.f);
        res.w = fmaxf(o3 + bias1[c0 + 3], 0.f);
        *(float4*)&out[(size_t)(bg * NB + n) * 256 + c0] = res;
    }
}

extern "C" void kernel_launch(void* const* d_in, const int* in_sizes, int n_in,
                              void* d_out, int out_size, void* d_ws, size_t ws_size,
                              hipStream_t stream) {
    const float* x     = (const float*)d_in[0];
    const float* Wl0   = (const float*)d_in[1];
    const float* bl0   = (const float*)d_in[2];
    const float* Wr0   = (const float*)d_in[3];
    const float* br0   = (const float*)d_in[4];
    const float* att0  = (const float*)d_in[5];
    const float* bias0 = (const float*)d_in[6];
    const float* Wl1   = (const float*)d_in[7];
    const float* bl1   = (const float*)d_in[8];
    const float* Wr1   = (const float*)d_in[9];
    const float* br1   = (const float*)d_in[10];
    const float* att1  = (const float*)d_in[11];
    const float* bias1 = (const float*)d_in[12];
    _Float16* wt = (_Float16*)d_ws;   // 512 KB
    float* out = (float*)d_out;

    prep_weights<<<64, 256, 0, stream>>>(Wl0, Wr0, Wl1, Wr1, wt);

    const size_t X1_off  = 524288;                              // wt region
    const size_t X1_size = (size_t)131072 * 512 * 2;            // 128 MiB f16
    if (ws_size >= X1_off + X1_size) {
        _Float16* X1 = (_Float16*)((char*)d_ws + X1_off);
        gemm0<<<1024, 512, 0, stream>>>(x, bl0, br0, wt, X1);
        gat_attn<<<NNODES / NB, 512, 0, stream>>>(att0, bias0, bl1, br1,
                                                  att1, bias1, wt, X1, out);
    } else {
        gat_fused<<<NNODES / NB, 512, 0, stream>>>(x, bl0, br0, att0, bias0,
                                                   bl1, br1, att1, bias1, wt, out);
    }
}

// Round 9
// 366.603 us; speedup vs baseline: 1.2489x; 1.0201x over previous
//
#include <hip/hip_runtime.h>

// MetapathGATConv for MI355X (gfx950) — R12.
// R11: gemm0 195->124us (A-reuse + b-dbuf), zero spills, but still
// latency-bound (all pipes <21%): 17 full barriers/block, each draining
// vmcnt(0) (all X1 stores + b loads) before any wave proceeds; epilogue
// half-idles waves. R12: gemm0 writes X1 in MFMA-native "strip" layout
// ([rb][nq][wc][mn][lane][r], f16x4/lane = 512B/wave contiguous) straight
// from acc -> Cb bounce and 16 of 17 barriers GONE (LDS 64KB, A only).
// gat_attn stage decodes the strip (coalesced f16x4 reads + 4 ds_write_b16,
// 2-way bank alias = free); P2..P7 untouched. Predicted: gemm0 ~75-90us,
// WRITE =131072KB, attn enters top-5 (~100-110) giving its counters.

#define NNODES 16384
#define NB 8
#define MR 64              // rows per WG in attention kernel = NB*8

typedef _Float16 f16x8 __attribute__((ext_vector_type(8)));
typedef _Float16 f16x4 __attribute__((ext_vector_type(4)));
typedef _Float16 f16x2 __attribute__((ext_vector_type(2)));
typedef float f32x4 __attribute__((ext_vector_type(4)));

#if __has_builtin(__builtin_amdgcn_fdot2)
#define FDOT2(a, b, c) __builtin_amdgcn_fdot2((a), (b), (c), false)
#else
#define FDOT2(a, b, c) ((c) + (float)(a)[0] * (float)(b)[0] + (float)(a)[1] * (float)(b)[1])
#endif

__device__ __forceinline__ f16x2 pk2(float a, float b) {
    return __builtin_bit_cast(f16x2, __builtin_amdgcn_cvt_pkrtz(a, b));
}

__device__ __forceinline__ f16x2 leaky2(f16x2 t) {
#if __has_builtin(__builtin_elementwise_max)
    return __builtin_elementwise_max(t, t * (f16x2){(_Float16)0.2f, (_Float16)0.2f});
#else
    const unsigned u = __builtin_bit_cast(unsigned, t) & 0x7FFF7FFFu;
    const f16x2 at = __builtin_bit_cast(f16x2, u);
    return t * (f16x2){(_Float16)0.6f, (_Float16)0.6f} +
           at * (f16x2){(_Float16)0.4f, (_Float16)0.4f};
#endif
}
__device__ __forceinline__ f16x2 relu2(f16x2 t) {
#if __has_builtin(__builtin_elementwise_max)
    return __builtin_elementwise_max(t, (f16x2){(_Float16)0.f, (_Float16)0.f});
#else
    const unsigned u = __builtin_bit_cast(unsigned, t) & 0x7FFF7FFFu;
    const f16x2 at = __builtin_bit_cast(f16x2, u);
    return (t + at) * (f16x2){(_Float16)0.5f, (_Float16)0.5f};
#endif
}

// swizzled chunk address: buffers are [rows][32 chunks of 8 f16],
// chunk index XORed with (row&7) so column-strided accesses spread banks.
__device__ __forceinline__ int swz(int row, int chunk) {
    return row * 256 + ((chunk ^ (row & 7)) << 3);
}

// ---------------- weight prep: transpose+cast to f16 W^T[n][k] ----------------
// wt rows 0-255: Wl0^T | 256-511: Wr0^T | 512-767: Wl1^T | 768-1023: Wr1^T.
__global__ void prep_weights(const float* __restrict__ Wl0, const float* __restrict__ Wr0,
                             const float* __restrict__ Wl1, const float* __restrict__ Wr1,
                             _Float16* __restrict__ wt) {
    __shared__ float tile[64 * 68];   // 64x64 + pad 4
    const int t  = threadIdx.x;
    const int m  = blockIdx.x >> 4;
    const int kt = (blockIdx.x >> 2) & 3;
    const int nt = blockIdx.x & 3;
    const float* src = (m == 0 ? Wl0 : m == 1 ? Wr0 : m == 2 ? Wl1 : Wr1) + kt * 64 * 256;
    #pragma unroll
    for (int i = 0; i < 4; ++i) {
        const int idx = i * 256 + t;     // float4 id 0..1023
        const int kk  = idx >> 4;
        const int nn  = (idx & 15) * 4;
        const float4 v = *(const float4*)&src[kk * 256 + nt * 64 + nn];
        tile[kk * 68 + nn + 0] = v.x;
        tile[kk * 68 + nn + 1] = v.y;
        tile[kk * 68 + nn + 2] = v.z;
        tile[kk * 68 + nn + 3] = v.w;
    }
    __syncthreads();
    const int n  = t >> 2;
    const int ks = (t & 3) * 16;
    f16x8 o0, o1;
    #pragma unroll
    for (int e = 0; e < 8; ++e) o0[e] = (_Float16)tile[(ks + e) * 68 + n];
    #pragma unroll
    for (int e = 0; e < 8; ++e) o1[e] = (_Float16)tile[(ks + 8 + e) * 68 + n];
    _Float16* dst = &wt[(size_t)(m * 256 + nt * 64 + n) * 256 + kt * 64 + ks];
    *(f16x8*)dst = o0;
    *(f16x8*)(dst + 8) = o1;
}

// ---------------- K1: X1strip = relu(x) @ [Wl0|Wr0] + [bl0|br0] ----------------
// Block = 128 rows; loops 4 n-quarters of 128 cols on the staged A tile.
// Wave (wr,wc) = 64 rows x 32 cols, acc[4][2]=32 regs, b double-buffered.
// Stores go DIRECTLY from acc to X1 in strip layout:
//   X1[rb][nq][wc][mn][lane][r]  (f16; rb = mb*2+wr, mn = m*2+n)
//   row(in rb) = m*16 + (lane>>4)*4 + r ; col = nq*128 + wc*32 + n*16 + (lane&15)
// -> f16x4 per lane, 512B contiguous per wave store; ONE barrier per block.
__launch_bounds__(512, 4)
__global__ void gemm0(const float* __restrict__ x,
                      const float* __restrict__ bl0, const float* __restrict__ br0,
                      const _Float16* __restrict__ wt,
                      _Float16* __restrict__ X1) {
    __shared__ _Float16 A[128 * 256];   // 64 KB: relu(x) f16 tile
    const int mb   = blockIdx.x;
    const int row0 = mb * 128;
    const int tid  = threadIdx.x;
    const int lane = tid & 63;
    const int wv   = tid >> 6;          // 0..7
    const int lr   = lane & 15;
    const int lq   = lane >> 4;
    const int wr   = wv >> 2;           // 0..1: rows wr*64..+63
    const int wc   = wv & 3;            // 0..3: cols wc*32..+31 within quarter

    // stage A = f16(relu(x[row0..row0+127][:]))
    {
        const float4* src = (const float4*)(x + (size_t)row0 * 256);
        #pragma unroll
        for (int it = 0; it < 8; ++it) {
            const int g = it * 512 + tid;    // chunk id 0..4095: row=g>>5, c=g&31
            const int row = g >> 5, c = g & 31;
            const float4 v0 = src[2 * g];
            const float4 v1 = src[2 * g + 1];
            f16x8 s;
            s[0] = (_Float16)fmaxf(v0.x, 0.f); s[1] = (_Float16)fmaxf(v0.y, 0.f);
            s[2] = (_Float16)fmaxf(v0.z, 0.f); s[3] = (_Float16)fmaxf(v0.w, 0.f);
            s[4] = (_Float16)fmaxf(v1.x, 0.f); s[5] = (_Float16)fmaxf(v1.y, 0.f);
            s[6] = (_Float16)fmaxf(v1.z, 0.f); s[7] = (_Float16)fmaxf(v1.w, 0.f);
            *(f16x8*)&A[swz(row, c)] = s;
        }
    }
    __syncthreads();   // the ONLY barrier

    for (int nq = 0; nq < 4; ++nq) {
        f32x4 acc[4][2];
        #pragma unroll
        for (int m = 0; m < 4; ++m)
            #pragma unroll
            for (int n = 0; n < 2; ++n)
                acc[m][n] = f32x4{0.f, 0.f, 0.f, 0.f};
        const _Float16* wq = wt + (size_t)(nq * 128 + wc * 32) * 256;
        // b double-buffer: preload kt=0
        f16x8 b[2][2];
        b[0][0] = *(const f16x8*)&wq[(size_t)lr * 256 + lq * 8];
        b[0][1] = *(const f16x8*)&wq[(size_t)(16 + lr) * 256 + lq * 8];
        #pragma unroll
        for (int kt = 0; kt < 8; ++kt) {
            const int cur = kt & 1, nxt = cur ^ 1;
            if (kt < 7) {
                const int koff = (kt + 1) * 32 + lq * 8;
                b[nxt][0] = *(const f16x8*)&wq[(size_t)lr * 256 + koff];
                b[nxt][1] = *(const f16x8*)&wq[(size_t)(16 + lr) * 256 + koff];
            }
            #pragma unroll
            for (int m = 0; m < 4; ++m) {
                const f16x8 a = *(const f16x8*)&A[swz(wr * 64 + m * 16 + lr, kt * 4 + lq)];
                #pragma unroll
                for (int n = 0; n < 2; ++n)
                    acc[m][n] = __builtin_amdgcn_mfma_f32_16x16x32_f16(a, b[cur][n], acc[m][n], 0, 0, 0);
            }
        }
        // direct strip stores (fire-and-forget; no barrier)
        const size_t sbase = (((size_t)(mb * 2 + wr) * 4 + nq) * 4 + wc) * (8 * 256);
        #pragma unroll
        for (int n = 0; n < 2; ++n) {
            const int gcol = nq * 128 + wc * 32 + n * 16 + lr;
            const float bias = (gcol < 256) ? bl0[gcol] : br0[gcol - 256];
            #pragma unroll
            for (int m = 0; m < 4; ++m) {
                f16x4 v;
                #pragma unroll
                for (int r = 0; r < 4; ++r) v[r] = (_Float16)(acc[m][n][r] + bias);
                *(f16x4*)&X1[sbase + (size_t)(m * 2 + n) * 256 + lane * 4] = v;
            }
        }
    }
}

// ---------------- K2: attention chain (P2..P7 verbatim; stage decodes strip) ----------------
__launch_bounds__(512, 4)
__global__ void gat_attn(const float* __restrict__ att0, const float* __restrict__ bias0,
                         const float* __restrict__ bl1, const float* __restrict__ br1,
                         const float* __restrict__ att1, const float* __restrict__ bias1,
                         const _Float16* __restrict__ wt,
                         const _Float16* __restrict__ X1,
                         float* __restrict__ out) {
    __shared__ _Float16 bufA[MR * 256];  // 32 KB: xr0 -> h1
    __shared__ _Float16 bufB[MR * 256];  // 32 KB: xl0 -> xl1
    __shared__ float attbuf[2304];       // 9 KB
    __shared__ _Float16 attH[768];       // 1.5 KB

    const int tid  = threadIdx.x;
    const int bg   = blockIdx.x;
    const int lane = tid & 63;
    const int wv   = tid >> 6;
    const int lr   = lane & 15;
    const int lq   = lane >> 4;

    // stage: decode strip layout for row-block bg -> bufB (xl, cols 0..255),
    // bufA (xr, cols 256..511). Coalesced f16x4 reads; 4 ds_write_b16 each
    // (2-way bank alias only). nq is wave-uniform -> no buf-select divergence.
    {
        const _Float16* src = X1 + (size_t)bg * 32768;
        #pragma unroll
        for (int i = 0; i < 16; ++i) {
            const int flat  = i * 512 + tid;       // 0..8191
            const int lane_s = flat & 63;
            const int mn  = (flat >> 6) & 7;
            const int wcq = (flat >> 9) & 3;
            const int nq  = flat >> 11;            // 0..3
            const int m = mn >> 1, n = mn & 1;
            const int lqs = lane_s >> 4, lrs = lane_s & 15;
            const f16x4 v = *(const f16x4*)&src[(((size_t)nq * 4 + wcq) * 8 + mn) * 256 + lane_s * 4];
            const int col = nq * 128 + wcq * 32 + n * 16 + lrs;   // 0..511
            _Float16* dst = (col < 256) ? bufB : bufA;
            const int cc = (col & 255) >> 3, ce = col & 7;
            const int rbase = m * 16 + lqs * 4;
            #pragma unroll
            for (int r = 0; r < 4; ++r)
                dst[swz(rbase + r, cc) + ce] = v[r];
        }
        if (tid < 256) {
            attH[tid]       = (_Float16)att0[tid];
            attH[512 + tid] = (_Float16)bias0[tid];
        } else {
            attH[tid]       = (_Float16)att1[tid - 256];
        }
    }
    __syncthreads();

    // ---------------- P2: layer-0 logits + softmax over j -> alpha0 ----------------
    {
        const int n  = tid >> 6;
        const int i  = (tid >> 3) & 7;
        const int h  = (tid >> 1) & 3;
        const int jh = tid & 1;
        const int rowR = n * 8 + i;
        f16x2 xr2[32];
        #pragma unroll
        for (int cc = 0; cc < 8; ++cc) {
            const int c3 = (cc + 2 * h) & 7;
            const f16x8 v = *(const f16x8*)&bufA[swz(rowR, h * 8 + c3)];
            xr2[cc * 4 + 0] = f16x2{v[0], v[1]};
            xr2[cc * 4 + 1] = f16x2{v[2], v[3]};
            xr2[cc * 4 + 2] = f16x2{v[4], v[5]};
            xr2[cc * 4 + 3] = f16x2{v[6], v[7]};
        }
        f16x8 lbuf[2][4];
        f16x8 abuf[2];
        {
            const int c3 = (2 * h) & 7;
            abuf[0] = *(const f16x8*)&attH[h * 64 + c3 * 8];
            #pragma unroll
            for (int jj = 0; jj < 4; ++jj)
                lbuf[0][jj] = *(const f16x8*)&bufB[swz(n * 8 + jh * 4 + jj, h * 8 + c3)];
        }
        float lg[4] = {0.f, 0.f, 0.f, 0.f};
        #pragma unroll
        for (int cc = 0; cc < 8; ++cc) {
            const int cur = cc & 1, nxt = cur ^ 1;
            if (cc < 7) {
                const int c3n = (cc + 1 + 2 * h) & 7;
                abuf[nxt] = *(const f16x8*)&attH[h * 64 + c3n * 8];
                #pragma unroll
                for (int jj = 0; jj < 4; ++jj)
                    lbuf[nxt][jj] = *(const f16x8*)&bufB[swz(n * 8 + jh * 4 + jj, h * 8 + c3n)];
            }
            const f16x8 a8 = abuf[cur];
            const f16x2 a2[4] = {{a8[0], a8[1]}, {a8[2], a8[3]}, {a8[4], a8[5]}, {a8[6], a8[7]}};
            #pragma unroll
            for (int jj = 0; jj < 4; ++jj) {
                const f16x8 l8 = lbuf[cur][jj];
                const f16x2 l2[4] = {{l8[0], l8[1]}, {l8[2], l8[3]}, {l8[4], l8[5]}, {l8[6], l8[7]}};
                #pragma unroll
                for (int p = 0; p < 4; ++p) {
                    const f16x2 t = leaky2(xr2[cc * 4 + p] + l2[p]);
                    lg[jj] = FDOT2(t, a2[p], lg[jj]);
                }
            }
        }
        float mx = fmaxf(fmaxf(lg[0], lg[1]), fmaxf(lg[2], lg[3]));
        mx = fmaxf(mx, __shfl_xor(mx, 1));
        float ex[4], ssum = 0.f;
        #pragma unroll
        for (int jj = 0; jj < 4; ++jj) { ex[jj] = __expf(lg[jj] - mx); ssum += ex[jj]; }
        const float tot = ssum + __shfl_xor(ssum, 1);
        const float inv = 1.f / tot;
        #pragma unroll
        for (int jj = 0; jj < 4; ++jj)
            attbuf[((n * 8 + i) * 4 + h) * 8 + jh * 4 + jj] = ex[jj] * inv;
    }
    __syncthreads();

    // ---------------- P3: h1 = relu(alpha0 @ xl0 + bias0) -> bufA ----------------
    {
        const int row  = tid >> 3;
        const int sub  = tid & 7;
        const int h    = sub >> 1;
        const int half = sub & 1;
        const int nn   = row >> 3;
        const int cb   = h * 8 + half * 4;
        _Float16 ahv[8];
        #pragma unroll
        for (int j = 0; j < 8; ++j) ahv[j] = (_Float16)attbuf[(row * 4 + h) * 8 + j];
        f16x2 acc2[16];
        #pragma unroll
        for (int p = 0; p < 16; ++p) acc2[p] = (f16x2){(_Float16)0.f, (_Float16)0.f};
        f16x8 vbuf[2][4];
        #pragma unroll
        for (int cc = 0; cc < 4; ++cc)
            vbuf[0][cc] = *(const f16x8*)&bufB[swz(nn * 8, cb + ((cc + h) & 3))];
        #pragma unroll
        for (int j = 0; j < 8; ++j) {
            const int cur = j & 1, nxt = cur ^ 1;
            if (j < 7) {
                #pragma unroll
                for (int cc = 0; cc < 4; ++cc)
                    vbuf[nxt][cc] = *(const f16x8*)&bufB[swz(nn * 8 + j + 1, cb + ((cc + h) & 3))];
            }
            const f16x2 a2 = {ahv[j], ahv[j]};
            #pragma unroll
            for (int cc = 0; cc < 4; ++cc) {
                const f16x8 v = vbuf[cur][cc];
                acc2[cc * 4 + 0] += f16x2{v[0], v[1]} * a2;
                acc2[cc * 4 + 1] += f16x2{v[2], v[3]} * a2;
                acc2[cc * 4 + 2] += f16x2{v[4], v[5]} * a2;
                acc2[cc * 4 + 3] += f16x2{v[6], v[7]} * a2;
            }
        }
        #pragma unroll
        for (int cc = 0; cc < 4; ++cc) {
            const int c = cb + ((cc + h) & 3);
            const f16x8 b8 = *(const f16x8*)&attH[512 + c * 8];
            f16x8 s;
            #pragma unroll
            for (int p = 0; p < 4; ++p) {
                const f16x2 r = relu2(acc2[cc * 4 + p] + f16x2{b8[2 * p], b8[2 * p + 1]});
                s[2 * p]     = r[0];
                s[2 * p + 1] = r[1];
            }
            *(f16x8*)&bufA[swz(row, c)] = s;
        }
    }
    __syncthreads();

    // ---------------- P5: GEMM1: xl1 -> bufB ; xrs -> attbuf ----------------
    {
        f32x4 accl[4][2], accr[2];
        #pragma unroll
        for (int m = 0; m < 4; ++m)
            #pragma unroll
            for (int n = 0; n < 2; ++n)
                accl[m][n] = f32x4{0.f, 0.f, 0.f, 0.f};
        #pragma unroll
        for (int n = 0; n < 2; ++n) accr[n] = f32x4{0.f, 0.f, 0.f, 0.f};
        const _Float16* W1l = wt + 512 * 256;
        const _Float16* W1r = wt + 768 * 256;
        const int rowS = (lr & 7) * 8 + 7;
        #pragma unroll
        for (int kt = 0; kt < 8; ++kt) {
            const int koff = kt * 32 + lq * 8;
            f16x8 a[4], as, bl[2], br[2];
            #pragma unroll
            for (int m = 0; m < 4; ++m)
                a[m] = *(const f16x8*)&bufA[swz(m * 16 + lr, kt * 4 + lq)];
            as = *(const f16x8*)&bufA[swz(rowS, kt * 4 + lq)];
            #pragma unroll
            for (int n = 0; n < 2; ++n) {
                bl[n] = *(const f16x8*)&W1l[(size_t)(wv * 32 + n * 16 + lr) * 256 + koff];
                br[n] = *(const f16x8*)&W1r[(size_t)(wv * 32 + n * 16 + lr) * 256 + koff];
            }
            #pragma unroll
            for (int m = 0; m < 4; ++m)
                #pragma unroll
                for (int n = 0; n < 2; ++n)
                    accl[m][n] = __builtin_amdgcn_mfma_f32_16x16x32_f16(a[m], bl[n], accl[m][n], 0, 0, 0);
            #pragma unroll
            for (int n = 0; n < 2; ++n)
                accr[n] = __builtin_amdgcn_mfma_f32_16x16x32_f16(as, br[n], accr[n], 0, 0, 0);
        }
        #pragma unroll
        for (int n = 0; n < 2; ++n) {
            const int col = wv * 32 + n * 16 + lr;
            const float b1 = bl1[col], b2 = br1[col];
            const int ch = col >> 3, ce = col & 7;
            #pragma unroll
            for (int m = 0; m < 4; ++m)
                #pragma unroll
                for (int r = 0; r < 4; ++r) {
                    const int row = m * 16 + lq * 4 + r;
                    bufB[swz(row, ch) + ce] = (_Float16)(accl[m][n][r] + b1);
                }
            if (lq < 2) {
                #pragma unroll
                for (int r = 0; r < 4; ++r) {
                    const int node = lq * 4 + r;
                    attbuf[node * 256 + col] = accr[n][r] + b2;
                }
            }
        }
    }
    __syncthreads();

    // ---------------- P6: layer-1 logits, softmax over r -> betas + alpha1 ----------------
    {
        const int n  = tid >> 5;
        const int rr = (tid >> 2) & 7;
        const int h  = tid & 3;
        float lg = 0.f;
        if (tid < 256) {
            const int rowj = n * 8 + rr;
            float4 xbuf0[2], xbuf1[2];
            f16x8 lbuf[2], abuf[2];
            {
                const int c = h * 8 + ((2 * h) & 7);
                xbuf0[0] = *(const float4*)&attbuf[n * 256 + c * 8];
                xbuf1[0] = *(const float4*)&attbuf[n * 256 + c * 8 + 4];
                lbuf[0]  = *(const f16x8*)&bufB[swz(rowj, c)];
                abuf[0]  = *(const f16x8*)&attH[256 + c * 8];
            }
            #pragma unroll
            for (int cc = 0; cc < 8; ++cc) {
                const int cur = cc & 1, nxt = cur ^ 1;
                if (cc < 7) {
                    const int cn = h * 8 + ((cc + 1 + 2 * h) & 7);
                    xbuf0[nxt] = *(const float4*)&attbuf[n * 256 + cn * 8];
                    xbuf1[nxt] = *(const float4*)&attbuf[n * 256 + cn * 8 + 4];
                    lbuf[nxt]  = *(const f16x8*)&bufB[swz(rowj, cn)];
                    abuf[nxt]  = *(const f16x8*)&attH[256 + cn * 8];
                }
                const float4 r0 = xbuf0[cur], r1 = xbuf1[cur];
                const f16x2 x2[4] = {pk2(r0.x, r0.y), pk2(r0.z, r0.w),
                                     pk2(r1.x, r1.y), pk2(r1.z, r1.w)};
                const f16x8 l8 = lbuf[cur];
                const f16x2 l2[4] = {{l8[0], l8[1]}, {l8[2], l8[3]}, {l8[4], l8[5]}, {l8[6], l8[7]}};
                const f16x8 a8 = abuf[cur];
                const f16x2 a2[4] = {{a8[0], a8[1]}, {a8[2], a8[3]}, {a8[4], a8[5]}, {a8[6], a8[7]}};
                #pragma unroll
                for (int p = 0; p < 4; ++p) {
                    const f16x2 t = leaky2(x2[p] + l2[p]);
                    lg = FDOT2(t, a2[p], lg);
                }
            }
        }
        __syncthreads();
        if (tid < 256) attbuf[2048 + tid] = lg;
        __syncthreads();
        if (tid < 256) {
            float M = -1e30f;
            float l[8];
            #pragma unroll
            for (int j = 0; j < 8; ++j) {
                l[j] = attbuf[2048 + n * 32 + j * 4 + h];
                M = fmaxf(M, l[j]);
            }
            float S = 0.f;
            #pragma unroll
            for (int j = 0; j < 8; ++j) S += __expf(l[j] - M);
            const float a = __expf(lg - M) / S;
            attbuf[tid] = a;
            out[(size_t)NNODES * 256 + (size_t)(bg * NB + n) * 32 + rr * 4 + h] = a;
        }
    }
    __syncthreads();

    // ---------------- P7: out = relu(alpha1 @ xl1 + bias1) ----------------
    {
        const int n  = tid >> 6;
        const int q  = tid & 63;
        const int c0 = q * 4;
        const int h  = q >> 4;
        f16x4 v[8];
        float a[8];
        #pragma unroll
        for (int r = 0; r < 8; ++r) {
            v[r] = *(const f16x4*)&bufB[swz(n * 8 + r, q >> 1) + (q & 1) * 4];
            a[r] = attbuf[n * 32 + r * 4 + h];
        }
        float o0 = 0.f, o1 = 0.f, o2 = 0.f, o3 = 0.f;
        #pragma unroll
        for (int r = 0; r < 8; ++r) {
            o0 = fmaf((float)v[r][0], a[r], o0);
            o1 = fmaf((float)v[r][1], a[r], o1);
            o2 = fmaf((float)v[r][2], a[r], o2);
            o3 = fmaf((float)v[r][3], a[r], o3);
        }
        float4 res;
        res.x = fmaxf(o0 + bias1[c0 + 0], 0.f);
        res.y = fmaxf(o1 + bias1[c0 + 1], 0.f);
        res.z = fmaxf(o2 + bias1[c0 + 2], 0.f);
        res.w = fmaxf(o3 + bias1[c0 + 3], 0.f);
        *(float4*)&out[(size_t)(bg * NB + n) * 256 + c0] = res;
    }
}

// ---------------- Fallback: R4 fused kernel, verbatim (201us proven) ----------------
__launch_bounds__(512, 4)
__global__ void gat_fused(const float* __restrict__ x,
                          const float* __restrict__ bl0, const float* __restrict__ br0,
                          const float* __restrict__ att0, const float* __restrict__ bias0,
                          const float* __restrict__ bl1, const float* __restrict__ br1,
                          const float* __restrict__ att1, const float* __restrict__ bias1,
                          const _Float16* __restrict__ wt,
                          float* __restrict__ out) {
    __shared__ _Float16 bufA[MR * 256];
    __shared__ _Float16 bufB[MR * 256];
    __shared__ float attbuf[2304];
    __shared__ _Float16 attH[768];

    const int tid  = threadIdx.x;
    const int bg   = blockIdx.x;
    const int lane = tid & 63;
    const int wv   = tid >> 6;
    const int lr   = lane & 15;
    const int lq   = lane >> 4;

    {
        const float4* src = (const float4*)(x + (size_t)bg * (MR * 256));
        #pragma unroll
        for (int it = 0; it < 4; ++it) {
            const int g   = it * 512 + tid;
            const int row = g >> 5;
            const int c   = g & 31;
            const float4 v0 = src[2 * g];
            const float4 v1 = src[2 * g + 1];
            f16x8 s;
            s[0] = (_Float16)fmaxf(v0.x, 0.f); s[1] = (_Float16)fmaxf(v0.y, 0.f);
            s[2] = (_Float16)fmaxf(v0.z, 0.f); s[3] = (_Float16)fmaxf(v0.w, 0.f);
            s[4] = (_Float16)fmaxf(v1.x, 0.f); s[5] = (_Float16)fmaxf(v1.y, 0.f);
            s[6] = (_Float16)fmaxf(v1.z, 0.f); s[7] = (_Float16)fmaxf(v1.w, 0.f);
            *(f16x8*)&bufA[swz(row, c)] = s;
        }
        if (tid < 256) {
            attH[tid]       = (_Float16)att0[tid];
            attH[512 + tid] = (_Float16)bias0[tid];
        } else {
            attH[tid]       = (_Float16)att1[tid - 256];
        }
    }
    __syncthreads();

    {
        f32x4 acc[4][4];
        #pragma unroll
        for (int m = 0; m < 4; ++m)
            #pragma unroll
            for (int n = 0; n < 4; ++n)
                acc[m][n] = f32x4{0.f, 0.f, 0.f, 0.f};
        #pragma unroll
        for (int kt = 0; kt < 8; ++kt) {
            f16x8 a[4], b[4];
            #pragma unroll
            for (int m = 0; m < 4; ++m)
                a[m] = *(const f16x8*)&bufA[swz(m * 16 + lr, kt * 4 + lq)];
            const int koff = kt * 32 + lq * 8;
            #pragma unroll
            for (int n = 0; n < 4; ++n)
                b[n] = *(const f16x8*)&wt[(size_t)(wv * 64 + n * 16 + lr) * 256 + koff];
            #pragma unroll
            for (int m = 0; m < 4; ++m)
                #pragma unroll
                for (int n = 0; n < 4; ++n)
                    acc[m][n] = __builtin_amdgcn_mfma_f32_16x16x32_f16(a[m], b[n], acc[m][n], 0, 0, 0);
        }
        __syncthreads();
        _Float16* dstbuf = (wv < 4) ? bufB : bufA;
        const float* bv = (wv < 4) ? bl0 : br0;
        #pragma unroll
        for (int n = 0; n < 4; ++n) {
            const int cl   = (wv & 3) * 64 + n * 16 + lr;
            const float bias = bv[cl];
            const int ch   = cl >> 3, ce = cl & 7;
            #pragma unroll
            for (int m = 0; m < 4; ++m)
                #pragma unroll
                for (int r = 0; r < 4; ++r) {
                    const int row = m * 16 + lq * 4 + r;
                    dstbuf[swz(row, ch) + ce] = (_Float16)(acc[m][n][r] + bias);
                }
        }
    }
    __syncthreads();

    {
        const int n  = tid >> 6;
        const int i  = (tid >> 3) & 7;
        const int h  = (tid >> 1) & 3;
        const int jh = tid & 1;
        const int rowR = n * 8 + i;
        f16x2 xr2[32];
        #pragma unroll
        for (int cc = 0; cc < 8; ++cc) {
            const int c3 = (cc + 2 * h) & 7;
            const f16x8 v = *(const f16x8*)&bufA[swz(rowR, h * 8 + c3)];
            xr2[cc * 4 + 0] = f16x2{v[0], v[1]};
            xr2[cc * 4 + 1] = f16x2{v[2], v[3]};
            xr2[cc * 4 + 2] = f16x2{v[4], v[5]};
            xr2[cc * 4 + 3] = f16x2{v[6], v[7]};
        }
        f16x8 lbuf[2][4];
        f16x8 abuf[2];
        {
            const int c3 = (2 * h) & 7;
            abuf[0] = *(const f16x8*)&attH[h * 64 + c3 * 8];
            #pragma unroll
            for (int jj = 0; jj < 4; ++jj)
                lbuf[0][jj] = *(const f16x8*)&bufB[swz(n * 8 + jh * 4 + jj, h * 8 + c3)];
        }
        float lg[4] = {0.f, 0.f, 0.f, 0.f};
        #pragma unroll
        for (int cc = 0; cc < 8; ++cc) {
            const int cur = cc & 1, nxt = cur ^ 1;
            if (cc < 7) {
                const int c3n = (cc + 1 + 2 * h) & 7;
                abuf[nxt] = *(const f16x8*)&attH[h * 64 + c3n * 8];
                #pragma unroll
                for (int jj = 0; jj < 4; ++jj)
                    lbuf[nxt][jj] = *(const f16x8*)&bufB[swz(n * 8 + jh * 4 + jj, h * 8 + c3n)];
            }
            const f16x8 a8 = abuf[cur];
            const f16x2 a2[4] = {{a8[0], a8[1]}, {a8[2], a8[3]}, {a8[4], a8[5]}, {a8[6], a8[7]}};
            #pragma unroll
            for (int jj = 0; jj < 4; ++jj) {
                const f16x8 l8 = lbuf[cur][jj];
                const f16x2 l2[4] = {{l8[0], l8[1]}, {l8[2], l8[3]}, {l8[4], l8[5]}, {l8[6], l8[7]}};
                #pragma unroll
                for (int p = 0; p < 4; ++p) {
                    const f16x2 t = leaky2(xr2[cc * 4 + p] + l2[p]);
                    lg[jj] = FDOT2(t, a2[p], lg[jj]);
                }
            }
        }
        float mx = fmaxf(fmaxf(lg[0], lg[1]), fmaxf(lg[2], lg[3]));
        mx = fmaxf(mx, __shfl_xor(mx, 1));
        float ex[4], ssum = 0.f;
        #pragma unroll
        for (int jj = 0; jj < 4; ++jj) { ex[jj] = __expf(lg[jj] - mx); ssum += ex[jj]; }
        const float tot = ssum + __shfl_xor(ssum, 1);
        const float inv = 1.f / tot;
        #pragma unroll
        for (int jj = 0; jj < 4; ++jj)
            attbuf[((n * 8 + i) * 4 + h) * 8 + jh * 4 + jj] = ex[jj] * inv;
    }
    __syncthreads();

    {
        const int row  = tid >> 3;
        const int sub  = tid & 7;
        const int h    = sub >> 1;
        const int half = sub & 1;
        const int nn   = row >> 3;
        const int cb   = h * 8 + half * 4;
        _Float16 ahv[8];
        #pragma unroll
        for (int j = 0; j < 8; ++j) ahv[j] = (_Float16)attbuf[(row * 4 + h) * 8 + j];
        f16x2 acc2[16];
        #pragma unroll
        for (int p = 0; p < 16; ++p) acc2[p] = (f16x2){(_Float16)0.f, (_Float16)0.f};
        f16x8 vbuf[2][4];
        #pragma unroll
        for (int cc = 0; cc < 4; ++cc)
            vbuf[0][cc] = *(const f16x8*)&bufB[swz(nn * 8, cb + ((cc + h) & 3))];
        #pragma unroll
        for (int j = 0; j < 8; ++j) {
            const int cur = j & 1, nxt = cur ^ 1;
            if (j < 7) {
                #pragma unroll
                for (int cc = 0; cc < 4; ++cc)
                    vbuf[nxt][cc] = *(const f16x8*)&bufB[swz(nn * 8 + j + 1, cb + ((cc + h) & 3))];
            }
            const f16x2 a2 = {ahv[j], ahv[j]};
            #pragma unroll
            for (int cc = 0; cc < 4; ++cc) {
                const f16x8 v = vbuf[cur][cc];
                acc2[cc * 4 + 0] += f16x2{v[0], v[1]} * a2;
                acc2[cc * 4 + 1] += f16x2{v[2], v[3]} * a2;
                acc2[cc * 4 + 2] += f16x2{v[4], v[5]} * a2;
                acc2[cc * 4 + 3] += f16x2{v[6], v[7]} * a2;
            }
        }
        #pragma unroll
        for (int cc = 0; cc < 4; ++cc) {
            const int c = cb + ((cc + h) & 3);
            const f16x8 b8 = *(const f16x8*)&attH[512 + c * 8];
            f16x8 s;
            #pragma unroll
            for (int p = 0; p < 4; ++p) {
                const f16x2 r = relu2(acc2[cc * 4 + p] + f16x2{b8[2 * p], b8[2 * p + 1]});
                s[2 * p]     = r[0];
                s[2 * p + 1] = r[1];
            }
            *(f16x8*)&bufA[swz(row, c)] = s;
        }
    }
    __syncthreads();

    {
        f32x4 accl[4][2], accr[2];
        #pragma unroll
        for (int m = 0; m < 4; ++m)
            #pragma unroll
            for (int n = 0; n < 2; ++n)
                accl[m][n] = f32x4{0.f, 0.f, 0.f, 0.f};
        #pragma unroll
        for (int n = 0; n < 2; ++n) accr[n] = f32x4{0.f, 0.f, 0.f, 0.f};
        const _Float16* W1l = wt + 512 * 256;
        const _Float16* W1r = wt + 768 * 256;
        const int rowS = (lr & 7) * 8 + 7;
        #pragma unroll
        for (int kt = 0; kt < 8; ++kt) {
            const int koff = kt * 32 + lq * 8;
            f16x8 a[4], as, bl[2], br[2];
            #pragma unroll
            for (int m = 0; m < 4; ++m)
                a[m] = *(const f16x8*)&bufA[swz(m * 16 + lr, kt * 4 + lq)];
            as = *(const f16x8*)&bufA[swz(rowS, kt * 4 + lq)];
            #pragma unroll
            for (int n = 0; n < 2; ++n) {
                bl[n] = *(const f16x8*)&W1l[(size_t)(wv * 32 + n * 16 + lr) * 256 + koff];
                br[n] = *(const f16x8*)&W1r[(size_t)(wv * 32 + n * 16 + lr) * 256 + koff];
            }
            #pragma unroll
            for (int m = 0; m < 4; ++m)
                #pragma unroll
                for (int n = 0; n < 2; ++n)
                    accl[m][n] = __builtin_amdgcn_mfma_f32_16x16x32_f16(a[m], bl[n], accl[m][n], 0, 0, 0);
            #pragma unroll
            for (int n = 0; n < 2; ++n)
                accr[n] = __builtin_amdgcn_mfma_f32_16x16x32_f16(as, br[n], accr[n], 0, 0, 0);
        }
        #pragma unroll
        for (int n = 0; n < 2; ++n) {
            const int col = wv * 32 + n * 16 + lr;
            const float b1 = bl1[col], b2 = br1[col];
            const int ch = col >> 3, ce = col & 7;
            #pragma unroll
            for (int m = 0; m < 4; ++m)
                #pragma unroll
                for (int r = 0; r < 4; ++r) {
                    const int row = m * 16 + lq * 4 + r;
                    bufB[swz(row, ch) + ce] = (_Float16)(accl[m][n][r] + b1);
                }
            if (lq < 2) {
                #pragma unroll
                for (int r = 0; r < 4; ++r) {
                    const int node = lq * 4 + r;
                    attbuf[node * 256 + col] = accr[n][r] + b2;
                }
            }
        }
    }
    __syncthreads();

    {
        const int n  = tid >> 5;
        const int rr = (tid >> 2) & 7;
        const int h  = tid & 3;
        float lg = 0.f;
        if (tid < 256) {
            const int rowj = n * 8 + rr;
            float4 xbuf0[2], xbuf1[2];
            f16x8 lbuf[2], abuf[2];
            {
                const int c = h * 8 + ((2 * h) & 7);
                xbuf0[0] = *(const float4*)&attbuf[n * 256 + c * 8];
                xbuf1[0] = *(const float4*)&attbuf[n * 256 + c * 8 + 4];
                lbuf[0]  = *(const f16x8*)&bufB[swz(rowj, c)];
                abuf[0]  = *(const f16x8*)&attH[256 + c * 8];
            }
            #pragma unroll
            for (int cc = 0; cc < 8; ++cc) {
                const int cur = cc & 1, nxt = cur ^ 1;
                if (cc < 7) {
                    const int cn = h * 8 + ((cc + 1 + 2 * h) & 7);
                    xbuf0[nxt] = *(const float4*)&attbuf[n * 256 + cn * 8];
                    xbuf1[nxt] = *(const float4*)&attbuf[n * 256 + cn * 8 + 4];
                    lbuf[nxt]  = *(const f16x8*)&bufB[swz(rowj, cn)];
                    abuf[nxt]  = *(const f16x8*)&attH[256 + cn * 8];
                }
                const float4 r0 = xbuf0[cur], r1 = xbuf1[cur];
                const f16x2 x2[4] = {pk2(r0.x, r0.y), pk2(r0.z, r0.w),
                                     pk2(r1.x, r1.y), pk2(r1.z, r1.w)};
                const f16x8 l8 = lbuf[cur];
                const f16x2 l2[4] = {{l8[0], l8[1]}, {l8[2], l8[3]}, {l8[4], l8[5]}, {l8[6], l8[7]}};
                const f16x8 a8 = abuf[cur];
                const f16x2 a2[4] = {{a8[0], a8[1]}, {a8[2], a8[3]}, {a8[4], a8[5]}, {a8[6], a8[7]}};
                #pragma unroll
                for (int p = 0; p < 4; ++p) {
                    const f16x2 t = leaky2(x2[p] + l2[p]);
                    lg = FDOT2(t, a2[p], lg);
                }
            }
        }
        __syncthreads();
        if (tid < 256) attbuf[2048 + tid] = lg;
        __syncthreads();
        if (tid < 256) {
            float M = -1e30f;
            float l[8];
            #pragma unroll
            for (int j = 0; j < 8; ++j) {
                l[j] = attbuf[2048 + n * 32 + j * 4 + h];
                M = fmaxf(M, l[j]);
            }
            float S = 0.f;
            #pragma unroll
            for (int j = 0; j < 8; ++j) S += __expf(l[j] - M);
            const float a = __expf(lg - M) / S;
            attbuf[tid] = a;
            out[(size_t)NNODES * 256 + (size_t)(bg * NB + n) * 32 + rr * 4 + h] = a;
        }
    }
    __syncthreads();

    {
        const int n  = tid >> 6;
        const int q  = tid & 63;
        const int c0 = q * 4;
        const int h  = q >> 4;
        f16x4 v[8];
        float a[8];
        #pragma unroll
        for (int r = 0; r < 8; ++r) {
            v[r] = *(const f16x4*)&bufB[swz(n * 8 + r, q >> 1) + (q & 1) * 4];
            a[r] = attbuf[n * 32 + r * 4 + h];
        }
        float o0 = 0.f, o1 = 0.f, o2 = 0.f, o3 = 0.f;
        #pragma unroll
        for (int r = 0; r < 8; ++r) {
            o0 = fmaf((float)v[r][0], a[r], o0);
            o1 = fmaf((float)v[r][1], a[r], o1);
            o2 = fmaf((float)v[r][2], a[r], o2);
            o3 = fmaf((float)v[r][3], a[r], o3);
        }
        float4 res;
        res.x = fmaxf(o0 + bias1[c0 + 0], 0.f);
        res.y = fmaxf(o1 + bias1[c0 + 1], 0.f);
        res.z = fmaxf(o2 + bias1[c0 + 2], 0.f);
        res.w = fmaxf(o3 + bias1[c0 + 3], 0.f);
        *(float4*)&out[(size_t)(bg * NB + n) * 256 + c0] = res;
    }
}

extern "C" void kernel_launch(void* const* d_in, const int* in_sizes, int n_in,
                              void* d_out, int out_size, void* d_ws, size_t ws_size,
                              hipStream_t stream) {
    const float* x     = (const float*)d_in[0];
    const float* Wl0   = (const float*)d_in[1];
    const float* bl0   = (const float*)d_in[2];
    const float* Wr0   = (const float*)d_in[3];
    const float* br0   = (const float*)d_in[4];
    const float* att0  = (const float*)d_in[5];
    const float* bias0 = (const float*)d_in[6];
    const float* Wl1   = (const float*)d_in[7];
    const float* bl1   = (const float*)d_in[8];
    const float* Wr1   = (const float*)d_in[9];
    const float* br1   = (const float*)d_in[10];
    const float* att1  = (const float*)d_in[11];
    const float* bias1 = (const float*)d_in[12];
    _Float16* wt = (_Float16*)d_ws;   // 512 KB
    float* out = (float*)d_out;

    prep_weights<<<64, 256, 0, stream>>>(Wl0, Wr0, Wl1, Wr1, wt);

    const size_t X1_off  = 524288;                              // wt region
    const size_t X1_size = (size_t)131072 * 512 * 2;            // 128 MiB f16
    if (ws_size >= X1_off + X1_size) {
        _Float16* X1 = (_Float16*)((char*)d_ws + X1_off);
        gemm0<<<1024, 512, 0, stream>>>(x, bl0, br0, wt, X1);
        gat_attn<<<NNODES / NB, 512, 0, stream>>>(att0, bias0, bl1, br1,
                                                  att1, bias1, wt, X1, out);
    } else {
        gat_fused<<<NNODES / NB, 512, 0, stream>>>(x, bl0, br0, att0, bias0,
                                                   bl1, br1, att1, bias1, wt, out);
    }
}